// Round 1
// baseline (1538.666 us; speedup 1.0000x reference)
//
#include <hip/hip_runtime.h>

#define D 128

// ---------------- degree histogram ----------------
__global__ void hist_k(const int* __restrict__ dst, int* __restrict__ cnt, int E) {
    int i = blockIdx.x * blockDim.x + threadIdx.x;
    if (i < E) atomicAdd(&cnt[dst[i]], 1);
}

// dinv[i] = rsqrt(cnt[i] + 1)   (self-loop included)
__global__ void dinv_k(const int* __restrict__ cnt, float* __restrict__ dinv, int n) {
    int i = blockIdx.x * blockDim.x + threadIdx.x;
    if (i < n) dinv[i] = rsqrtf((float)(cnt[i] + 1));
}

// ---------------- exclusive scan (3-pass) ----------------
__global__ void scan_bsum_k(const int* __restrict__ cnt, int* __restrict__ bsum, int n) {
    __shared__ int sh[256];
    int tid = threadIdx.x;
    int base = blockIdx.x * 1024 + tid * 4;
    int local = 0;
    #pragma unroll
    for (int j = 0; j < 4; ++j) if (base + j < n) local += cnt[base + j];
    sh[tid] = local;
    __syncthreads();
    for (int o = 128; o > 0; o >>= 1) {
        if (tid < o) sh[tid] += sh[tid + o];
        __syncthreads();
    }
    if (tid == 0) bsum[blockIdx.x] = sh[0];
}

__global__ void scan_serial_k(int* __restrict__ bsum, int nb) {
    if (threadIdx.x == 0 && blockIdx.x == 0) {
        int run = 0;
        for (int i = 0; i < nb; ++i) { int v = bsum[i]; bsum[i] = run; run += v; }
    }
}

__global__ void scan_final_k(const int* __restrict__ cnt, const int* __restrict__ bofs,
                             int* __restrict__ offs, int n) {
    __shared__ int sh[256];
    int tid = threadIdx.x;
    int base = blockIdx.x * 1024 + tid * 4;
    int v[4];
    int local = 0;
    #pragma unroll
    for (int j = 0; j < 4; ++j) {
        v[j] = (base + j < n) ? cnt[base + j] : 0;
        local += v[j];
    }
    sh[tid] = local;
    __syncthreads();
    for (int o = 1; o < 256; o <<= 1) {
        int t = (tid >= o) ? sh[tid - o] : 0;
        __syncthreads();
        sh[tid] += t;
        __syncthreads();
    }
    int run = sh[tid] - local + bofs[blockIdx.x];
    #pragma unroll
    for (int j = 0; j < 4; ++j) {
        if (base + j < n) { offs[base + j] = run; run += v[j]; }
    }
}

// ---------------- CSR scatter ----------------
__global__ void scatter_k(const int* __restrict__ src, const int* __restrict__ dst,
                          const int* __restrict__ offs, int* __restrict__ ctr,
                          int* __restrict__ csr, int E) {
    int i = blockIdx.x * blockDim.x + threadIdx.x;
    if (i < E) {
        int d = dst[i];
        int pos = offs[d] + atomicAdd(&ctr[d], 1);
        csr[pos] = src[i];
    }
}

// ---------------- GEMM: out[n][128] = x[n][128] @ W[128][128] ----------------
// 32 rows per block; x tile in LDS; W streamed (64KB, L1/L2 hot).
__global__ __launch_bounds__(256) void gemm_xw(const float* __restrict__ x,
                                               const float* __restrict__ W,
                                               float* __restrict__ out, int n) {
    __shared__ float xs[32 * D];
    int tid = threadIdx.x;
    long long rbase = (long long)blockIdx.x * 32;
    const float4* xin = (const float4*)(x + rbase * D);
    float4* xs4 = (float4*)xs;
    for (int i = tid; i < 32 * D / 4; i += 256) xs4[i] = xin[i];
    __syncthreads();
    int c = tid & 31;       // float4 column group: cols 4c..4c+3
    int rs = tid >> 5;      // row slot 0..7; rows rs, rs+8, rs+16, rs+24
    const float4* W4 = (const float4*)W;
    float4 a0 = {0,0,0,0}, a1 = {0,0,0,0}, a2 = {0,0,0,0}, a3 = {0,0,0,0};
    #pragma unroll 4
    for (int in = 0; in < D; ++in) {
        float4 w = W4[in * 32 + c];
        float x0 = xs[rs * D + in];
        float x1 = xs[(rs + 8) * D + in];
        float x2 = xs[(rs + 16) * D + in];
        float x3 = xs[(rs + 24) * D + in];
        a0.x = fmaf(x0, w.x, a0.x); a0.y = fmaf(x0, w.y, a0.y);
        a0.z = fmaf(x0, w.z, a0.z); a0.w = fmaf(x0, w.w, a0.w);
        a1.x = fmaf(x1, w.x, a1.x); a1.y = fmaf(x1, w.y, a1.y);
        a1.z = fmaf(x1, w.z, a1.z); a1.w = fmaf(x1, w.w, a1.w);
        a2.x = fmaf(x2, w.x, a2.x); a2.y = fmaf(x2, w.y, a2.y);
        a2.z = fmaf(x2, w.z, a2.z); a2.w = fmaf(x2, w.w, a2.w);
        a3.x = fmaf(x3, w.x, a3.x); a3.y = fmaf(x3, w.y, a3.y);
        a3.z = fmaf(x3, w.z, a3.z); a3.w = fmaf(x3, w.w, a3.w);
    }
    float4* o4 = (float4*)out;
    long long ob = rbase * 32;
    o4[ob + (rs) * 32 + c] = a0;
    o4[ob + (rs + 8) * 32 + c] = a1;
    o4[ob + (rs + 16) * 32 + c] = a2;
    o4[ob + (rs + 24) * 32 + c] = a3;
}

// ---------------- GCN aggregation ----------------
// one wave (64 lanes) per node; lane holds 2 features (float2).
// out[i] = dinv[i] * ( sum_{e: dst=i} dinv[src]*h[src] + dinv[i]*h[i] ) + b, opt relu
__global__ __launch_bounds__(256) void gcn_agg(const float* __restrict__ h,
                                               const float* __restrict__ dinv,
                                               const int* __restrict__ offs,
                                               const int* __restrict__ csr,
                                               const float* __restrict__ bias,
                                               float* __restrict__ out,
                                               int n, int nedges, int do_relu) {
    int wave = threadIdx.x >> 6;
    int lane = threadIdx.x & 63;
    int node = blockIdx.x * 4 + wave;
    if (node >= n) return;
    const float2* h2 = (const float2*)h;
    float di = dinv[node];
    float2 hv = h2[(long long)node * 64 + lane];
    float ax = di * hv.x, ay = di * hv.y;
    int e0 = offs[node];
    int e1 = (node + 1 < n) ? offs[node + 1] : nedges;
    for (int e = e0; e < e1; ++e) {
        int s = csr[e];
        float w = dinv[s];
        float2 sv = h2[(long long)s * 64 + lane];
        ax = fmaf(w, sv.x, ax);
        ay = fmaf(w, sv.y, ay);
    }
    float2 b2 = ((const float2*)bias)[lane];
    float ox = fmaf(di, ax, b2.x);
    float oy = fmaf(di, ay, b2.y);
    if (do_relu) { ox = fmaxf(ox, 0.f); oy = fmaxf(oy, 0.f); }
    ((float2*)out)[(long long)node * 64 + lane] = make_float2(ox, oy);
}

// ---------------- loss partials ----------------
// wave per pair (32 pairs per wave sequentially, 128 pairs per block).
// accum[0] += sum bce ; accum[1] += sum sigmoid(u·duW+dub) ; accum[2] += sum sigmoid(i·diW+dib)
__global__ __launch_bounds__(256) void loss_partial(const float* __restrict__ x,
                                                    const int* __restrict__ users,
                                                    const int* __restrict__ items,
                                                    const int* __restrict__ labels,
                                                    const float* __restrict__ clsW,
                                                    const float* __restrict__ clsb,
                                                    const float* __restrict__ duW,
                                                    const float* __restrict__ dub,
                                                    const float* __restrict__ diW,
                                                    const float* __restrict__ dib,
                                                    const int* __restrict__ numUserP,
                                                    float* __restrict__ accum, int Bn) {
    int tid = threadIdx.x;
    int lane = tid & 63;
    int wave = tid >> 6;
    float2 cA = ((const float2*)clsW)[lane];
    float2 cB = ((const float2*)clsW)[64 + lane];
    float2 wU = ((const float2*)duW)[lane];
    float2 wI = ((const float2*)diW)[lane];
    int nu = numUserP[0];
    const float2* x2 = (const float2*)x;
    float bceA = 0.f, cuA = 0.f, ciA = 0.f;
    int base = blockIdx.x * 128 + wave * 32;
    for (int p = 0; p < 32; ++p) {
        int k = base + p;
        if (k >= Bn) break;
        int u = users[k];
        int it = items[k] + nu;
        float2 uv = x2[(long long)u * 64 + lane];
        float2 iv = x2[(long long)it * 64 + lane];
        float zp = uv.x * cA.x + uv.y * cA.y + iv.x * cB.x + iv.y * cB.y;
        float up = uv.x * wU.x + uv.y * wU.y;
        float ip = iv.x * wI.x + iv.y * wI.y;
        #pragma unroll
        for (int o = 32; o > 0; o >>= 1) {
            zp += __shfl_xor(zp, o);
            up += __shfl_xor(up, o);
            ip += __shfl_xor(ip, o);
        }
        if (lane == 0) {
            float z = zp + clsb[0];
            float y = (float)labels[k];
            float sp = fmaxf(z, 0.f) + log1pf(expf(-fabsf(z)));
            bceA += sp - y * z;            // y*sp(-z)+(1-y)*sp(z) == sp(z)-y*z
            cuA += 1.f / (1.f + expf(-(up + dub[0])));
            ciA += 1.f / (1.f + expf(-(ip + dib[0])));
        }
    }
    __shared__ float sh[12];
    if (lane == 0) { sh[wave * 3 + 0] = bceA; sh[wave * 3 + 1] = cuA; sh[wave * 3 + 2] = ciA; }
    __syncthreads();
    if (tid < 3) {
        float v = sh[tid] + sh[3 + tid] + sh[6 + tid] + sh[9 + tid];
        atomicAdd(&accum[tid], v);
    }
}

// accum layout: [0..2] = domain s (bce,cu,ci) ; [3..5] = domain t
__global__ void finalize_k(const float* __restrict__ accum, float* __restrict__ out, float invB) {
    if (threadIdx.x == 0 && blockIdx.x == 0) {
        float clf = (accum[0] + accum[3]) * invB;
        float dom = fabsf((accum[1] - accum[4]) * invB) + fabsf((accum[2] - accum[5]) * invB);
        out[0] = clf + dom;
    }
}

extern "C" void kernel_launch(void* const* d_in, const int* in_sizes, int n_in,
                              void* d_out, int out_size, void* d_ws, size_t ws_size,
                              hipStream_t stream) {
    const float* feats_s = (const float*)d_in[0];
    const float* feats_t = (const float*)d_in[1];
    const float* W1   = (const float*)d_in[2];
    const float* b1   = (const float*)d_in[3];
    const float* W2   = (const float*)d_in[4];
    const float* b2   = (const float*)d_in[5];
    const float* clsW = (const float*)d_in[6];
    const float* clsb = (const float*)d_in[7];
    const float* duW  = (const float*)d_in[8];
    const float* dub  = (const float*)d_in[9];
    const float* diW  = (const float*)d_in[10];
    const float* dib  = (const float*)d_in[11];

    int N = in_sizes[0] / D;
    int E = in_sizes[12];
    int B = in_sizes[16];

    char* ws = (char*)d_ws;
    size_t off = 0;
    auto alloc = [&](size_t bytes) -> void* {
        void* p = ws + off;
        off += (bytes + 255) & ~(size_t)255;
        return p;
    };
    float* dinv  = (float*)alloc((size_t)N * 4);
    int*   cnt   = (int*)  alloc((size_t)N * 4);
    int*   ctr   = (int*)  alloc((size_t)N * 4);
    int*   offs  = (int*)  alloc((size_t)(N + 1) * 4);
    int*   bsum  = (int*)  alloc(4096);
    int*   csr   = (int*)  alloc((size_t)E * 4);
    float* bufA  = (float*)alloc((size_t)N * D * 4);
    float* bufB  = (float*)alloc((size_t)N * D * 4);
    float* accum = (float*)alloc(128);

    hipMemsetAsync(accum, 0, 6 * sizeof(float), stream);

    int nb = (N + 1023) / 1024;

    for (int dm = 0; dm < 2; ++dm) {
        const float* feats = dm ? feats_t : feats_s;
        const int* esrc = (const int*)d_in[dm ? 14 : 12];
        const int* edst = (const int*)d_in[dm ? 15 : 13];
        const int* user = (const int*)d_in[dm ? 19 : 16];
        const int* item = (const int*)d_in[dm ? 20 : 17];
        const int* lab  = (const int*)d_in[dm ? 21 : 18];
        const int* nup  = (const int*)d_in[dm ? 23 : 22];

        hipMemsetAsync(cnt, 0, (size_t)N * 4, stream);
        hipMemsetAsync(ctr, 0, (size_t)N * 4, stream);

        hist_k<<<(E + 255) / 256, 256, 0, stream>>>(edst, cnt, E);
        dinv_k<<<(N + 255) / 256, 256, 0, stream>>>(cnt, dinv, N);
        scan_bsum_k<<<nb, 256, 0, stream>>>(cnt, bsum, N);
        scan_serial_k<<<1, 64, 0, stream>>>(bsum, nb);
        scan_final_k<<<nb, 256, 0, stream>>>(cnt, bsum, offs, N);
        scatter_k<<<(E + 255) / 256, 256, 0, stream>>>(esrc, edst, offs, ctr, csr, E);

        gemm_xw<<<N / 32, 256, 0, stream>>>(feats, W1, bufA, N);
        gcn_agg<<<(N + 3) / 4, 256, 0, stream>>>(bufA, dinv, offs, csr, b1, bufB, N, E, 1);
        gemm_xw<<<N / 32, 256, 0, stream>>>(bufB, W2, bufA, N);
        gcn_agg<<<(N + 3) / 4, 256, 0, stream>>>(bufA, dinv, offs, csr, b2, bufB, N, E, 0);

        loss_partial<<<(B + 127) / 128, 256, 0, stream>>>(bufB, user, item, lab,
                                                          clsW, clsb, duW, dub, diW, dib,
                                                          nup, accum + 3 * dm, B);
    }

    finalize_k<<<1, 64, 0, stream>>>(accum, (float*)d_out, 1.0f / (float)B);
}

// Round 2
// 1143.276 us; speedup vs baseline: 1.3458x; 1.3458x over previous
//
#include <hip/hip_runtime.h>

#define D 128

// ---------- bf16 pack/unpack (RNE) ----------
static __device__ inline unsigned pack_bf16x2(float a, float b) {
    unsigned ua = __float_as_uint(a);
    unsigned ub = __float_as_uint(b);
    ua += 0x7fffu + ((ua >> 16) & 1u);
    ub += 0x7fffu + ((ub >> 16) & 1u);
    return (ua >> 16) | (ub & 0xffff0000u);
}
static __device__ inline float bf_lo(unsigned u) { return __uint_as_float(u << 16); }
static __device__ inline float bf_hi(unsigned u) { return __uint_as_float(u & 0xffff0000u); }

// ---------------- degree histogram ----------------
__global__ void hist_k(const int* __restrict__ dst, int* __restrict__ cnt, int E) {
    int i = blockIdx.x * blockDim.x + threadIdx.x;
    if (i < E) atomicAdd(&cnt[dst[i]], 1);
}

// dinv[i] = rsqrt(cnt[i] + 1)   (self-loop included)
__global__ void dinv_k(const int* __restrict__ cnt, float* __restrict__ dinv, int n) {
    int i = blockIdx.x * blockDim.x + threadIdx.x;
    if (i < n) dinv[i] = rsqrtf((float)(cnt[i] + 1));
}

// ---------------- exclusive scan (3-pass) ----------------
__global__ void scan_bsum_k(const int* __restrict__ cnt, int* __restrict__ bsum, int n) {
    __shared__ int sh[256];
    int tid = threadIdx.x;
    int base = blockIdx.x * 1024 + tid * 4;
    int local = 0;
    #pragma unroll
    for (int j = 0; j < 4; ++j) if (base + j < n) local += cnt[base + j];
    sh[tid] = local;
    __syncthreads();
    for (int o = 128; o > 0; o >>= 1) {
        if (tid < o) sh[tid] += sh[tid + o];
        __syncthreads();
    }
    if (tid == 0) bsum[blockIdx.x] = sh[0];
}

__global__ void scan_serial_k(int* __restrict__ bsum, int nb) {
    if (threadIdx.x == 0 && blockIdx.x == 0) {
        int run = 0;
        for (int i = 0; i < nb; ++i) { int v = bsum[i]; bsum[i] = run; run += v; }
    }
}

__global__ void scan_final_k(const int* __restrict__ cnt, const int* __restrict__ bofs,
                             int* __restrict__ offs, int n) {
    __shared__ int sh[256];
    int tid = threadIdx.x;
    int base = blockIdx.x * 1024 + tid * 4;
    int v[4];
    int local = 0;
    #pragma unroll
    for (int j = 0; j < 4; ++j) {
        v[j] = (base + j < n) ? cnt[base + j] : 0;
        local += v[j];
    }
    sh[tid] = local;
    __syncthreads();
    for (int o = 1; o < 256; o <<= 1) {
        int t = (tid >= o) ? sh[tid - o] : 0;
        __syncthreads();
        sh[tid] += t;
        __syncthreads();
    }
    int run = sh[tid] - local + bofs[blockIdx.x];
    #pragma unroll
    for (int j = 0; j < 4; ++j) {
        if (base + j < n) { offs[base + j] = run; run += v[j]; }
    }
}

// ---------------- CSR scatter ----------------
__global__ void scatter_k(const int* __restrict__ src, const int* __restrict__ dst,
                          const int* __restrict__ offs, int* __restrict__ ctr,
                          int* __restrict__ csr, int E) {
    int i = blockIdx.x * blockDim.x + threadIdx.x;
    if (i < E) {
        int d = dst[i];
        int pos = offs[d] + atomicAdd(&ctr[d], 1);
        csr[pos] = src[i];
    }
}

// ---------------- GEMM: outb[n][128](bf16) = x[n][128] @ W[128][128] ----------------
// 32 rows per block; x tile in LDS; W streamed (64KB, L1/L2 hot).
__global__ __launch_bounds__(256) void gemm_xw(const float* __restrict__ x,
                                               const float* __restrict__ W,
                                               unsigned* __restrict__ outb, int n) {
    __shared__ float xs[32 * D];
    int tid = threadIdx.x;
    long long rbase = (long long)blockIdx.x * 32;
    const float4* xin = (const float4*)(x + rbase * D);
    float4* xs4 = (float4*)xs;
    for (int i = tid; i < 32 * D / 4; i += 256) xs4[i] = xin[i];
    __syncthreads();
    int c = tid & 31;       // float4 column group: cols 4c..4c+3
    int rs = tid >> 5;      // row slot 0..7; rows rs, rs+8, rs+16, rs+24
    const float4* W4 = (const float4*)W;
    float4 a0 = {0,0,0,0}, a1 = {0,0,0,0}, a2 = {0,0,0,0}, a3 = {0,0,0,0};
    #pragma unroll 4
    for (int in = 0; in < D; ++in) {
        float4 w = W4[in * 32 + c];
        float x0 = xs[rs * D + in];
        float x1 = xs[(rs + 8) * D + in];
        float x2 = xs[(rs + 16) * D + in];
        float x3 = xs[(rs + 24) * D + in];
        a0.x = fmaf(x0, w.x, a0.x); a0.y = fmaf(x0, w.y, a0.y);
        a0.z = fmaf(x0, w.z, a0.z); a0.w = fmaf(x0, w.w, a0.w);
        a1.x = fmaf(x1, w.x, a1.x); a1.y = fmaf(x1, w.y, a1.y);
        a1.z = fmaf(x1, w.z, a1.z); a1.w = fmaf(x1, w.w, a1.w);
        a2.x = fmaf(x2, w.x, a2.x); a2.y = fmaf(x2, w.y, a2.y);
        a2.z = fmaf(x2, w.z, a2.z); a2.w = fmaf(x2, w.w, a2.w);
        a3.x = fmaf(x3, w.x, a3.x); a3.y = fmaf(x3, w.y, a3.y);
        a3.z = fmaf(x3, w.z, a3.z); a3.w = fmaf(x3, w.w, a3.w);
    }
    // pack to bf16: row = 64 uints; this thread owns uint2 slot c of each row
    uint2* o2 = (uint2*)outb;
    long long ob = rbase * 32;   // uint2 per row = 32
    uint2 p0 = { pack_bf16x2(a0.x, a0.y), pack_bf16x2(a0.z, a0.w) };
    uint2 p1 = { pack_bf16x2(a1.x, a1.y), pack_bf16x2(a1.z, a1.w) };
    uint2 p2 = { pack_bf16x2(a2.x, a2.y), pack_bf16x2(a2.z, a2.w) };
    uint2 p3 = { pack_bf16x2(a3.x, a3.y), pack_bf16x2(a3.z, a3.w) };
    o2[ob + (rs) * 32 + c] = p0;
    o2[ob + (rs + 8) * 32 + c] = p1;
    o2[ob + (rs + 16) * 32 + c] = p2;
    o2[ob + (rs + 24) * 32 + c] = p3;
}

// ---------------- GCN aggregation ----------------
// one wave (64 lanes) per node; lane holds 2 features (packed bf16 in one uint).
// out[i] = dinv[i] * ( sum_{e: dst=i} dinv[src]*h[src] + dinv[i]*h[i] ) + b, opt relu
// 8-wide masked unroll: 8 outstanding gathers per wave.
__global__ __launch_bounds__(256) void gcn_agg(const unsigned* __restrict__ hb,
                                               const float* __restrict__ dinv,
                                               const int* __restrict__ offs,
                                               const int* __restrict__ csr,
                                               const float* __restrict__ bias,
                                               float* __restrict__ out,
                                               int n, int nedges, int do_relu) {
    int wave = threadIdx.x >> 6;
    int lane = threadIdx.x & 63;
    int node = blockIdx.x * 4 + wave;
    if (node >= n) return;
    float di = dinv[node];
    unsigned hv = hb[(long long)node * 64 + lane];
    float ax = di * bf_lo(hv), ay = di * bf_hi(hv);
    int e0 = offs[node];
    int e1 = (node + 1 < n) ? offs[node + 1] : nedges;
    for (int e = e0; e < e1; e += 8) {
        int idx[8];
        #pragma unroll
        for (int j = 0; j < 8; ++j) {
            int ee = e + j;
            idx[j] = csr[ee < e1 ? ee : e1 - 1];
        }
        float w[8]; unsigned u[8];
        #pragma unroll
        for (int j = 0; j < 8; ++j) {
            w[j] = (e + j < e1) ? dinv[idx[j]] : 0.f;
            u[j] = hb[(long long)idx[j] * 64 + lane];
        }
        #pragma unroll
        for (int j = 0; j < 8; ++j) {
            ax = fmaf(w[j], bf_lo(u[j]), ax);
            ay = fmaf(w[j], bf_hi(u[j]), ay);
        }
    }
    float2 b2 = ((const float2*)bias)[lane];
    float ox = fmaf(di, ax, b2.x);
    float oy = fmaf(di, ay, b2.y);
    if (do_relu) { ox = fmaxf(ox, 0.f); oy = fmaxf(oy, 0.f); }
    ((float2*)out)[(long long)node * 64 + lane] = make_float2(ox, oy);
}

// ---------------- loss partials ----------------
__global__ __launch_bounds__(256) void loss_partial(const float* __restrict__ x,
                                                    const int* __restrict__ users,
                                                    const int* __restrict__ items,
                                                    const int* __restrict__ labels,
                                                    const float* __restrict__ clsW,
                                                    const float* __restrict__ clsb,
                                                    const float* __restrict__ duW,
                                                    const float* __restrict__ dub,
                                                    const float* __restrict__ diW,
                                                    const float* __restrict__ dib,
                                                    const int* __restrict__ numUserP,
                                                    float* __restrict__ accum, int Bn) {
    int tid = threadIdx.x;
    int lane = tid & 63;
    int wave = tid >> 6;
    float2 cA = ((const float2*)clsW)[lane];
    float2 cB = ((const float2*)clsW)[64 + lane];
    float2 wU = ((const float2*)duW)[lane];
    float2 wI = ((const float2*)diW)[lane];
    int nu = numUserP[0];
    const float2* x2 = (const float2*)x;
    float bceA = 0.f, cuA = 0.f, ciA = 0.f;
    int base = blockIdx.x * 128 + wave * 32;
    for (int p = 0; p < 32; ++p) {
        int k = base + p;
        if (k >= Bn) break;
        int u = users[k];
        int it = items[k] + nu;
        float2 uv = x2[(long long)u * 64 + lane];
        float2 iv = x2[(long long)it * 64 + lane];
        float zp = uv.x * cA.x + uv.y * cA.y + iv.x * cB.x + iv.y * cB.y;
        float up = uv.x * wU.x + uv.y * wU.y;
        float ip = iv.x * wI.x + iv.y * wI.y;
        #pragma unroll
        for (int o = 32; o > 0; o >>= 1) {
            zp += __shfl_xor(zp, o);
            up += __shfl_xor(up, o);
            ip += __shfl_xor(ip, o);
        }
        if (lane == 0) {
            float z = zp + clsb[0];
            float y = (float)labels[k];
            float sp = fmaxf(z, 0.f) + log1pf(expf(-fabsf(z)));
            bceA += sp - y * z;            // y*sp(-z)+(1-y)*sp(z) == sp(z)-y*z
            cuA += 1.f / (1.f + expf(-(up + dub[0])));
            ciA += 1.f / (1.f + expf(-(ip + dib[0])));
        }
    }
    __shared__ float sh[12];
    if (lane == 0) { sh[wave * 3 + 0] = bceA; sh[wave * 3 + 1] = cuA; sh[wave * 3 + 2] = ciA; }
    __syncthreads();
    if (tid < 3) {
        float v = sh[tid] + sh[3 + tid] + sh[6 + tid] + sh[9 + tid];
        atomicAdd(&accum[tid], v);
    }
}

// accum layout: [0..2] = domain s (bce,cu,ci) ; [3..5] = domain t
__global__ void finalize_k(const float* __restrict__ accum, float* __restrict__ out, float invB) {
    if (threadIdx.x == 0 && blockIdx.x == 0) {
        float clf = (accum[0] + accum[3]) * invB;
        float dom = fabsf((accum[1] - accum[4]) * invB) + fabsf((accum[2] - accum[5]) * invB);
        out[0] = clf + dom;
    }
}

extern "C" void kernel_launch(void* const* d_in, const int* in_sizes, int n_in,
                              void* d_out, int out_size, void* d_ws, size_t ws_size,
                              hipStream_t stream) {
    const float* feats_s = (const float*)d_in[0];
    const float* feats_t = (const float*)d_in[1];
    const float* W1   = (const float*)d_in[2];
    const float* b1   = (const float*)d_in[3];
    const float* W2   = (const float*)d_in[4];
    const float* b2   = (const float*)d_in[5];
    const float* clsW = (const float*)d_in[6];
    const float* clsb = (const float*)d_in[7];
    const float* duW  = (const float*)d_in[8];
    const float* dub  = (const float*)d_in[9];
    const float* diW  = (const float*)d_in[10];
    const float* dib  = (const float*)d_in[11];

    int N = in_sizes[0] / D;
    int E = in_sizes[12];
    int B = in_sizes[16];

    char* ws = (char*)d_ws;
    size_t off = 0;
    auto alloc = [&](size_t bytes) -> void* {
        void* p = ws + off;
        off += (bytes + 255) & ~(size_t)255;
        return p;
    };
    float*    dinv  = (float*)alloc((size_t)N * 4);
    int*      cnt   = (int*)  alloc((size_t)N * 4);
    int*      ctr   = (int*)  alloc((size_t)N * 4);
    int*      offs  = (int*)  alloc((size_t)(N + 1) * 4);
    int*      bsum  = (int*)  alloc(4096);
    int*      csr   = (int*)  alloc((size_t)E * 4);
    unsigned* hbuf  = (unsigned*)alloc((size_t)N * (D / 2) * 4);  // bf16 h (packed)
    float*    bufB  = (float*)alloc((size_t)N * D * 4);           // f32 agg out
    float*    accum = (float*)alloc(128);

    hipMemsetAsync(accum, 0, 6 * sizeof(float), stream);

    int nb = (N + 1023) / 1024;

    for (int dm = 0; dm < 2; ++dm) {
        const float* feats = dm ? feats_t : feats_s;
        const int* esrc = (const int*)d_in[dm ? 14 : 12];
        const int* edst = (const int*)d_in[dm ? 15 : 13];
        const int* user = (const int*)d_in[dm ? 19 : 16];
        const int* item = (const int*)d_in[dm ? 20 : 17];
        const int* lab  = (const int*)d_in[dm ? 21 : 18];
        const int* nup  = (const int*)d_in[dm ? 23 : 22];

        hipMemsetAsync(cnt, 0, (size_t)N * 4, stream);
        hipMemsetAsync(ctr, 0, (size_t)N * 4, stream);

        hist_k<<<(E + 255) / 256, 256, 0, stream>>>(edst, cnt, E);
        dinv_k<<<(N + 255) / 256, 256, 0, stream>>>(cnt, dinv, N);
        scan_bsum_k<<<nb, 256, 0, stream>>>(cnt, bsum, N);
        scan_serial_k<<<1, 64, 0, stream>>>(bsum, nb);
        scan_final_k<<<nb, 256, 0, stream>>>(cnt, bsum, offs, N);
        scatter_k<<<(E + 255) / 256, 256, 0, stream>>>(esrc, edst, offs, ctr, csr, E);

        gemm_xw<<<N / 32, 256, 0, stream>>>(feats, W1, hbuf, N);
        gcn_agg<<<(N + 3) / 4, 256, 0, stream>>>(hbuf, dinv, offs, csr, b1, bufB, N, E, 1);
        gemm_xw<<<N / 32, 256, 0, stream>>>(bufB, W2, hbuf, N);
        gcn_agg<<<(N + 3) / 4, 256, 0, stream>>>(hbuf, dinv, offs, csr, b2, bufB, N, E, 0);

        loss_partial<<<(B + 127) / 128, 256, 0, stream>>>(bufB, user, item, lab,
                                                          clsW, clsb, duW, dub, diW, dib,
                                                          nup, accum + 3 * dm, B);
    }

    finalize_k<<<1, 64, 0, stream>>>(accum, (float*)d_out, 1.0f / (float)B);
}

// Round 3
// 943.997 us; speedup vs baseline: 1.6299x; 1.2111x over previous
//
#include <hip/hip_runtime.h>

#define D 128

// ---------- bf16 pack/unpack (RNE) ----------
static __device__ inline unsigned pack_bf16x2(float a, float b) {
    unsigned ua = __float_as_uint(a);
    unsigned ub = __float_as_uint(b);
    ua += 0x7fffu + ((ua >> 16) & 1u);
    ub += 0x7fffu + ((ub >> 16) & 1u);
    return (ua >> 16) | (ub & 0xffff0000u);
}
static __device__ inline float bf_lo(unsigned u) { return __uint_as_float(u << 16); }
static __device__ inline float bf_hi(unsigned u) { return __uint_as_float(u & 0xffff0000u); }

// ================= CSR build via 2-level bucket sort =================
// bucket b = dst >> 8  (256 nodes per bucket)

// ---- bucket histogram ----
__global__ __launch_bounds__(256) void bh_k(const int* __restrict__ dst,
                                            int* __restrict__ bcnt, int E) {
    __shared__ int h[512];
    for (int i = threadIdx.x; i < 512; i += 256) h[i] = 0;
    __syncthreads();
    int stride = gridDim.x * 256;
    for (int e = blockIdx.x * 256 + threadIdx.x; e < E; e += stride)
        atomicAdd(&h[dst[e] >> 8], 1);
    __syncthreads();
    for (int i = threadIdx.x; i < 512; i += 256)
        if (h[i]) atomicAdd(&bcnt[i], h[i]);
}

// ---- exclusive scan of 512 bucket counts (one block) ----
__global__ __launch_bounds__(512) void scan512_k(const int* __restrict__ bcnt,
                                                 int* __restrict__ bbase,
                                                 int* __restrict__ cursor, int nb) {
    __shared__ int sh[512];
    int t = threadIdx.x;
    int v = (t < nb) ? bcnt[t] : 0;
    sh[t] = v;
    __syncthreads();
    for (int o = 1; o < 512; o <<= 1) {
        int x = (t >= o) ? sh[t - o] : 0;
        __syncthreads();
        sh[t] += x;
        __syncthreads();
    }
    int excl = sh[t] - v;
    if (t < nb) { bbase[t] = excl; cursor[t] = excl; }
    if (t == 0) bbase[nb] = sh[511];
}

// ---- bin edges into bucket regions as packed records: src | (dst&255)<<24 ----
__global__ __launch_bounds__(256) void bin_k(const int* __restrict__ src,
                                             const int* __restrict__ dst,
                                             int* __restrict__ cursor,
                                             unsigned* __restrict__ pairs, int E) {
    __shared__ int h[512];
    __shared__ int gb[512];
    int t0 = blockIdx.x * 2048;
    if (t0 >= E) return;
    for (int i = threadIdx.x; i < 512; i += 256) h[i] = 0;
    __syncthreads();
    int rank[8]; unsigned pk[8]; short bk[8];
    #pragma unroll
    for (int j = 0; j < 8; ++j) {
        int e = t0 + j * 256 + threadIdx.x;
        if (e < E) {
            int d = dst[e], s = src[e];
            bk[j] = (short)(d >> 8);
            pk[j] = (unsigned)s | ((unsigned)(d & 255) << 24);
            rank[j] = atomicAdd(&h[d >> 8], 1);
        } else bk[j] = -1;
    }
    __syncthreads();
    for (int i = threadIdx.x; i < 512; i += 256)
        gb[i] = h[i] ? atomicAdd(&cursor[i], h[i]) : 0;
    __syncthreads();
    #pragma unroll
    for (int j = 0; j < 8; ++j)
        if (bk[j] >= 0) pairs[gb[bk[j]] + rank[j]] = pk[j];
}

// ---- per-bucket: node counts -> offs/dinv, then local scatter into csr ----
__global__ __launch_bounds__(256) void csr_build_k(const unsigned* __restrict__ pairs,
                                                   const int* __restrict__ bbase,
                                                   int* __restrict__ offs,
                                                   float* __restrict__ dinv,
                                                   int* __restrict__ csr, int N) {
    __shared__ int lh[256];
    __shared__ int lex[256];
    __shared__ int lc[256];
    int b = blockIdx.x;
    int t = threadIdx.x;
    int e0 = bbase[b], e1 = bbase[b + 1];
    lh[t] = 0; lc[t] = 0;
    __syncthreads();
    for (int e = e0 + t; e < e1; e += 256)
        atomicAdd(&lh[pairs[e] >> 24], 1);
    __syncthreads();
    int v = lh[t];
    lex[t] = v;
    __syncthreads();
    for (int o = 1; o < 256; o <<= 1) {
        int x = (t >= o) ? lex[t - o] : 0;
        __syncthreads();
        lex[t] += x;
        __syncthreads();
    }
    int excl = lex[t] - v;
    int node = (b << 8) + t;
    if (node < N) {
        offs[node] = e0 + excl;
        dinv[node] = rsqrtf((float)(v + 1));
    }
    lex[t] = excl;              // own-slot overwrite; cross-thread reads after barrier
    __syncthreads();
    for (int e = e0 + t; e < e1; e += 256) {
        unsigned p = pairs[e];
        int d = p >> 24;
        int pos = lex[d] + atomicAdd(&lc[d], 1);
        csr[e0 + pos] = (int)(p & 0xffffffu);
    }
}

// ---------------- GEMM: outb[n][128](bf16) = x[n][128] @ W[128][128] ----------------
__global__ __launch_bounds__(256) void gemm_xw(const float* __restrict__ x,
                                               const float* __restrict__ W,
                                               unsigned* __restrict__ outb, int n) {
    __shared__ float xs[32 * D];
    int tid = threadIdx.x;
    long long rbase = (long long)blockIdx.x * 32;
    const float4* xin = (const float4*)(x + rbase * D);
    float4* xs4 = (float4*)xs;
    for (int i = tid; i < 32 * D / 4; i += 256) xs4[i] = xin[i];
    __syncthreads();
    int c = tid & 31;
    int rs = tid >> 5;
    const float4* W4 = (const float4*)W;
    float4 a0 = {0,0,0,0}, a1 = {0,0,0,0}, a2 = {0,0,0,0}, a3 = {0,0,0,0};
    #pragma unroll 4
    for (int in = 0; in < D; ++in) {
        float4 w = W4[in * 32 + c];
        float x0 = xs[rs * D + in];
        float x1 = xs[(rs + 8) * D + in];
        float x2 = xs[(rs + 16) * D + in];
        float x3 = xs[(rs + 24) * D + in];
        a0.x = fmaf(x0, w.x, a0.x); a0.y = fmaf(x0, w.y, a0.y);
        a0.z = fmaf(x0, w.z, a0.z); a0.w = fmaf(x0, w.w, a0.w);
        a1.x = fmaf(x1, w.x, a1.x); a1.y = fmaf(x1, w.y, a1.y);
        a1.z = fmaf(x1, w.z, a1.z); a1.w = fmaf(x1, w.w, a1.w);
        a2.x = fmaf(x2, w.x, a2.x); a2.y = fmaf(x2, w.y, a2.y);
        a2.z = fmaf(x2, w.z, a2.z); a2.w = fmaf(x2, w.w, a2.w);
        a3.x = fmaf(x3, w.x, a3.x); a3.y = fmaf(x3, w.y, a3.y);
        a3.z = fmaf(x3, w.z, a3.z); a3.w = fmaf(x3, w.w, a3.w);
    }
    uint2* o2 = (uint2*)outb;
    long long ob = rbase * 32;
    uint2 p0 = { pack_bf16x2(a0.x, a0.y), pack_bf16x2(a0.z, a0.w) };
    uint2 p1 = { pack_bf16x2(a1.x, a1.y), pack_bf16x2(a1.z, a1.w) };
    uint2 p2 = { pack_bf16x2(a2.x, a2.y), pack_bf16x2(a2.z, a2.w) };
    uint2 p3 = { pack_bf16x2(a3.x, a3.y), pack_bf16x2(a3.z, a3.w) };
    o2[ob + (rs) * 32 + c] = p0;
    o2[ob + (rs + 8) * 32 + c] = p1;
    o2[ob + (rs + 16) * 32 + c] = p2;
    o2[ob + (rs + 24) * 32 + c] = p3;
}

// ---------------- GCN aggregation ----------------
__global__ __launch_bounds__(256) void gcn_agg(const unsigned* __restrict__ hb,
                                               const float* __restrict__ dinv,
                                               const int* __restrict__ offs,
                                               const int* __restrict__ csr,
                                               const float* __restrict__ bias,
                                               float* __restrict__ out,
                                               int n, int nedges, int do_relu) {
    int wave = threadIdx.x >> 6;
    int lane = threadIdx.x & 63;
    int node = blockIdx.x * 4 + wave;
    if (node >= n) return;
    float di = dinv[node];
    unsigned hv = hb[(long long)node * 64 + lane];
    float ax = di * bf_lo(hv), ay = di * bf_hi(hv);
    int e0 = offs[node];
    int e1 = (node + 1 < n) ? offs[node + 1] : nedges;
    for (int e = e0; e < e1; e += 8) {
        int idx[8];
        #pragma unroll
        for (int j = 0; j < 8; ++j) {
            int ee = e + j;
            idx[j] = csr[ee < e1 ? ee : e1 - 1];
        }
        float w[8]; unsigned u[8];
        #pragma unroll
        for (int j = 0; j < 8; ++j) {
            w[j] = (e + j < e1) ? dinv[idx[j]] : 0.f;
            u[j] = hb[(long long)idx[j] * 64 + lane];
        }
        #pragma unroll
        for (int j = 0; j < 8; ++j) {
            ax = fmaf(w[j], bf_lo(u[j]), ax);
            ay = fmaf(w[j], bf_hi(u[j]), ay);
        }
    }
    float2 b2 = ((const float2*)bias)[lane];
    float ox = fmaf(di, ax, b2.x);
    float oy = fmaf(di, ay, b2.y);
    if (do_relu) { ox = fmaxf(ox, 0.f); oy = fmaxf(oy, 0.f); }
    ((float2*)out)[(long long)node * 64 + lane] = make_float2(ox, oy);
}

// ---------------- loss partials ----------------
__global__ __launch_bounds__(256) void loss_partial(const float* __restrict__ x,
                                                    const int* __restrict__ users,
                                                    const int* __restrict__ items,
                                                    const int* __restrict__ labels,
                                                    const float* __restrict__ clsW,
                                                    const float* __restrict__ clsb,
                                                    const float* __restrict__ duW,
                                                    const float* __restrict__ dub,
                                                    const float* __restrict__ diW,
                                                    const float* __restrict__ dib,
                                                    const int* __restrict__ numUserP,
                                                    float* __restrict__ accum, int Bn) {
    int tid = threadIdx.x;
    int lane = tid & 63;
    int wave = tid >> 6;
    float2 cA = ((const float2*)clsW)[lane];
    float2 cB = ((const float2*)clsW)[64 + lane];
    float2 wU = ((const float2*)duW)[lane];
    float2 wI = ((const float2*)diW)[lane];
    int nu = numUserP[0];
    const float2* x2 = (const float2*)x;
    float bceA = 0.f, cuA = 0.f, ciA = 0.f;
    int base = blockIdx.x * 128 + wave * 32;
    for (int p = 0; p < 32; ++p) {
        int k = base + p;
        if (k >= Bn) break;
        int u = users[k];
        int it = items[k] + nu;
        float2 uv = x2[(long long)u * 64 + lane];
        float2 iv = x2[(long long)it * 64 + lane];
        float zp = uv.x * cA.x + uv.y * cA.y + iv.x * cB.x + iv.y * cB.y;
        float up = uv.x * wU.x + uv.y * wU.y;
        float ip = iv.x * wI.x + iv.y * wI.y;
        #pragma unroll
        for (int o = 32; o > 0; o >>= 1) {
            zp += __shfl_xor(zp, o);
            up += __shfl_xor(up, o);
            ip += __shfl_xor(ip, o);
        }
        if (lane == 0) {
            float z = zp + clsb[0];
            float y = (float)labels[k];
            float sp = fmaxf(z, 0.f) + log1pf(expf(-fabsf(z)));
            bceA += sp - y * z;
            cuA += 1.f / (1.f + expf(-(up + dub[0])));
            ciA += 1.f / (1.f + expf(-(ip + dib[0])));
        }
    }
    __shared__ float sh[12];
    if (lane == 0) { sh[wave * 3 + 0] = bceA; sh[wave * 3 + 1] = cuA; sh[wave * 3 + 2] = ciA; }
    __syncthreads();
    if (tid < 3) {
        float v = sh[tid] + sh[3 + tid] + sh[6 + tid] + sh[9 + tid];
        atomicAdd(&accum[tid], v);
    }
}

__global__ void finalize_k(const float* __restrict__ accum, float* __restrict__ out, float invB) {
    if (threadIdx.x == 0 && blockIdx.x == 0) {
        float clf = (accum[0] + accum[3]) * invB;
        float dom = fabsf((accum[1] - accum[4]) * invB) + fabsf((accum[2] - accum[5]) * invB);
        out[0] = clf + dom;
    }
}

extern "C" void kernel_launch(void* const* d_in, const int* in_sizes, int n_in,
                              void* d_out, int out_size, void* d_ws, size_t ws_size,
                              hipStream_t stream) {
    const float* feats_s = (const float*)d_in[0];
    const float* feats_t = (const float*)d_in[1];
    const float* W1   = (const float*)d_in[2];
    const float* b1   = (const float*)d_in[3];
    const float* W2   = (const float*)d_in[4];
    const float* b2   = (const float*)d_in[5];
    const float* clsW = (const float*)d_in[6];
    const float* clsb = (const float*)d_in[7];
    const float* duW  = (const float*)d_in[8];
    const float* dub  = (const float*)d_in[9];
    const float* diW  = (const float*)d_in[10];
    const float* dib  = (const float*)d_in[11];

    int N = in_sizes[0] / D;
    int E = in_sizes[12];
    int B = in_sizes[16];
    int nb = (N + 255) >> 8;    // buckets of 256 nodes

    char* ws = (char*)d_ws;
    size_t off = 0;
    auto alloc = [&](size_t bytes) -> void* {
        void* p = ws + off;
        off += (bytes + 255) & ~(size_t)255;
        return p;
    };
    float*    dinv   = (float*)alloc((size_t)N * 4);
    int*      offs   = (int*)  alloc((size_t)(N + 1) * 4);
    int*      bcnt   = (int*)  alloc(512 * 4);
    int*      bbase  = (int*)  alloc(513 * 4);
    int*      cursor = (int*)  alloc(512 * 4);
    unsigned* pairs  = (unsigned*)alloc((size_t)E * 4);
    int*      csr    = (int*)  alloc((size_t)E * 4);
    unsigned* hbuf   = (unsigned*)alloc((size_t)N * (D / 2) * 4);  // bf16 h (packed)
    float*    bufB   = (float*)alloc((size_t)N * D * 4);           // f32 agg out
    float*    accum  = (float*)alloc(128);

    hipMemsetAsync(accum, 0, 6 * sizeof(float), stream);

    for (int dm = 0; dm < 2; ++dm) {
        const float* feats = dm ? feats_t : feats_s;
        const int* esrc = (const int*)d_in[dm ? 14 : 12];
        const int* edst = (const int*)d_in[dm ? 15 : 13];
        const int* user = (const int*)d_in[dm ? 19 : 16];
        const int* item = (const int*)d_in[dm ? 20 : 17];
        const int* lab  = (const int*)d_in[dm ? 21 : 18];
        const int* nup  = (const int*)d_in[dm ? 23 : 22];

        hipMemsetAsync(bcnt, 0, 512 * 4, stream);
        bh_k<<<782, 256, 0, stream>>>(edst, bcnt, E);
        scan512_k<<<1, 512, 0, stream>>>(bcnt, bbase, cursor, nb);
        bin_k<<<(E + 2047) / 2048, 256, 0, stream>>>(esrc, edst, cursor, pairs, E);
        csr_build_k<<<nb, 256, 0, stream>>>(pairs, bbase, offs, dinv, csr, N);

        gemm_xw<<<N / 32, 256, 0, stream>>>(feats, W1, hbuf, N);
        gcn_agg<<<(N + 3) / 4, 256, 0, stream>>>(hbuf, dinv, offs, csr, b1, bufB, N, E, 1);
        gemm_xw<<<N / 32, 256, 0, stream>>>(bufB, W2, hbuf, N);
        gcn_agg<<<(N + 3) / 4, 256, 0, stream>>>(hbuf, dinv, offs, csr, b2, bufB, N, E, 0);

        loss_partial<<<(B + 127) / 128, 256, 0, stream>>>(bufB, user, item, lab,
                                                          clsW, clsb, duW, dub, diW, dib,
                                                          nup, accum + 3 * dm, B);
    }

    finalize_k<<<1, 64, 0, stream>>>(accum, (float*)d_out, 1.0f / (float)B);
}

// Round 4
// 781.236 us; speedup vs baseline: 1.9695x; 1.2083x over previous
//
#include <hip/hip_runtime.h>

#define D 128

typedef __attribute__((ext_vector_type(8))) short bf16x8;
typedef __attribute__((ext_vector_type(4))) float f32x4;

// ---------- bf16 pack/unpack (RNE) ----------
static __device__ inline unsigned pack_bf16x2(float a, float b) {
    unsigned ua = __float_as_uint(a);
    unsigned ub = __float_as_uint(b);
    ua += 0x7fffu + ((ua >> 16) & 1u);
    ub += 0x7fffu + ((ub >> 16) & 1u);
    return (ua >> 16) | (ub & 0xffff0000u);
}
static __device__ inline float bf_lo(unsigned u) { return __uint_as_float(u << 16); }
static __device__ inline float bf_hi(unsigned u) { return __uint_as_float(u & 0xffff0000u); }

// ================= CSR build via 2-level bucket sort =================
// bucket b = dst >> 8  (256 nodes per bucket)

__global__ __launch_bounds__(256) void bh_k(const int* __restrict__ dst,
                                            int* __restrict__ bcnt, int E) {
    __shared__ int h[512];
    for (int i = threadIdx.x; i < 512; i += 256) h[i] = 0;
    __syncthreads();
    int stride = gridDim.x * 256;
    for (int e = blockIdx.x * 256 + threadIdx.x; e < E; e += stride)
        atomicAdd(&h[dst[e] >> 8], 1);
    __syncthreads();
    for (int i = threadIdx.x; i < 512; i += 256)
        if (h[i]) atomicAdd(&bcnt[i], h[i]);
}

__global__ __launch_bounds__(512) void scan512_k(const int* __restrict__ bcnt,
                                                 int* __restrict__ bbase,
                                                 int* __restrict__ cursor, int nb) {
    __shared__ int sh[512];
    int t = threadIdx.x;
    int v = (t < nb) ? bcnt[t] : 0;
    sh[t] = v;
    __syncthreads();
    for (int o = 1; o < 512; o <<= 1) {
        int x = (t >= o) ? sh[t - o] : 0;
        __syncthreads();
        sh[t] += x;
        __syncthreads();
    }
    int excl = sh[t] - v;
    if (t < nb) { bbase[t] = excl; cursor[t] = excl; }
    if (t == 0) bbase[nb] = sh[511];
}

__global__ __launch_bounds__(256) void bin_k(const int* __restrict__ src,
                                             const int* __restrict__ dst,
                                             int* __restrict__ cursor,
                                             unsigned* __restrict__ pairs, int E) {
    __shared__ int h[512];
    __shared__ int gb[512];
    int t0 = blockIdx.x * 2048;
    if (t0 >= E) return;
    for (int i = threadIdx.x; i < 512; i += 256) h[i] = 0;
    __syncthreads();
    int rank[8]; unsigned pk[8]; short bk[8];
    #pragma unroll
    for (int j = 0; j < 8; ++j) {
        int e = t0 + j * 256 + threadIdx.x;
        if (e < E) {
            int d = dst[e], s = src[e];
            bk[j] = (short)(d >> 8);
            pk[j] = (unsigned)s | ((unsigned)(d & 255) << 24);
            rank[j] = atomicAdd(&h[d >> 8], 1);
        } else bk[j] = -1;
    }
    __syncthreads();
    for (int i = threadIdx.x; i < 512; i += 256)
        gb[i] = h[i] ? atomicAdd(&cursor[i], h[i]) : 0;
    __syncthreads();
    #pragma unroll
    for (int j = 0; j < 8; ++j)
        if (bk[j] >= 0) pairs[gb[bk[j]] + rank[j]] = pk[j];
}

__global__ __launch_bounds__(256) void csr_build_k(const unsigned* __restrict__ pairs,
                                                   const int* __restrict__ bbase,
                                                   int* __restrict__ offs,
                                                   float* __restrict__ dinv,
                                                   int* __restrict__ csr, int N) {
    __shared__ int lh[256];
    __shared__ int lex[256];
    __shared__ int lc[256];
    int b = blockIdx.x;
    int t = threadIdx.x;
    int e0 = bbase[b], e1 = bbase[b + 1];
    lh[t] = 0; lc[t] = 0;
    __syncthreads();
    for (int e = e0 + t; e < e1; e += 256)
        atomicAdd(&lh[pairs[e] >> 24], 1);
    __syncthreads();
    int v = lh[t];
    lex[t] = v;
    __syncthreads();
    for (int o = 1; o < 256; o <<= 1) {
        int x = (t >= o) ? lex[t - o] : 0;
        __syncthreads();
        lex[t] += x;
        __syncthreads();
    }
    int excl = lex[t] - v;
    int node = (b << 8) + t;
    if (node < N) {
        offs[node] = e0 + excl;
        dinv[node] = rsqrtf((float)(v + 1));
    }
    lex[t] = excl;
    __syncthreads();
    for (int e = e0 + t; e < e1; e += 256) {
        unsigned p = pairs[e];
        int d = p >> 24;
        int pos = lex[d] + atomicAdd(&lc[d], 1);
        csr[e0 + pos] = (int)(p & 0xffffffu);
    }
}

// ================= MFMA GEMM =================
// Pack W (128x128 f32) into B-fragment order for mfma_f32_16x16x32_bf16:
// wp[((t*4+c)*64 + lane)*8 + j] = bf16( W[c*32 + (lane>>4)*8 + j][t*16 + (lane&15)] )
__global__ __launch_bounds__(256) void packW_k(const float* __restrict__ W1,
                                               const float* __restrict__ W2,
                                               unsigned short* __restrict__ wp1,
                                               unsigned short* __restrict__ wp2) {
    const float* W = blockIdx.x ? W2 : W1;
    unsigned short* wp = blockIdx.x ? wp2 : wp1;
    for (int idx = threadIdx.x; idx < 2048; idx += 256) {
        int f = idx >> 6, lane = idx & 63;
        int t = f >> 2, c = f & 3;
        int q = lane >> 4, nn = lane & 15;
        #pragma unroll
        for (int j = 0; j < 8; ++j) {
            unsigned u = __float_as_uint(W[(c * 32 + q * 8 + j) * 128 + t * 16 + nn]);
            u += 0x7fffu + ((u >> 16) & 1u);
            wp[idx * 8 + j] = (unsigned short)(u >> 16);
        }
    }
}

// outb[n][128](packed bf16) = bf16(x[n][128]) @ bf16(W) ; f32 accumulate in MFMA
// block = 4 waves x 16 rows = 64 rows
__global__ __launch_bounds__(256) void gemm_mfma(const float* __restrict__ x,
                                                 const unsigned short* __restrict__ wp,
                                                 unsigned* __restrict__ outb, int n) {
    __shared__ float cs[64 * 132];   // +4 pad breaks 4-quad bank aliasing
    int tid = threadIdx.x;
    int wave = tid >> 6, lane = tid & 63;
    int quad = lane >> 4, nn = lane & 15;
    long long blockbase = (long long)blockIdx.x * 64;
    long long ar = blockbase + wave * 16 + nn;
    if (ar > n - 1) ar = n - 1;                 // tail clamp (result discarded)
    const float4* xr = (const float4*)(x + ar * 128);

    bf16x8 a[4];
    #pragma unroll
    for (int c = 0; c < 4; ++c) {
        float4 lo = xr[c * 8 + quad * 2];
        float4 hi = xr[c * 8 + quad * 2 + 1];
        union { bf16x8 v; unsigned u[4]; } au;
        au.u[0] = pack_bf16x2(lo.x, lo.y);
        au.u[1] = pack_bf16x2(lo.z, lo.w);
        au.u[2] = pack_bf16x2(hi.x, hi.y);
        au.u[3] = pack_bf16x2(hi.z, hi.w);
        a[c] = au.v;
    }

    f32x4 acc[8];
    #pragma unroll
    for (int t = 0; t < 8; ++t) acc[t] = (f32x4){0.f, 0.f, 0.f, 0.f};

    const bf16x8* wf = (const bf16x8*)wp;
    #pragma unroll
    for (int t = 0; t < 8; ++t) {
        #pragma unroll
        for (int c = 0; c < 4; ++c) {
            bf16x8 b = wf[(t * 4 + c) * 64 + lane];
            acc[t] = __builtin_amdgcn_mfma_f32_16x16x32_bf16(a[c], b, acc[t], 0, 0, 0);
        }
    }

    // C/D: row = quad*4 + r (within wave slab), col = 16t + nn
    #pragma unroll
    for (int t = 0; t < 8; ++t) {
        #pragma unroll
        for (int r = 0; r < 4; ++r)
            cs[(wave * 16 + quad * 4 + r) * 132 + t * 16 + nn] = acc[t][r];
    }
    __syncthreads();

    uint2* o2 = (uint2*)outb;
    #pragma unroll
    for (int i = 0; i < 8; ++i) {
        int idx = tid + i * 256;
        int r = idx >> 5, c4 = idx & 31;
        const float4 v = *(const float4*)&cs[r * 132 + c4 * 4];
        if (blockbase + r < n)
            o2[(blockbase + r) * 32 + c4] =
                make_uint2(pack_bf16x2(v.x, v.y), pack_bf16x2(v.z, v.w));
    }
}

// ---------------- GCN aggregation ----------------
__global__ __launch_bounds__(256) void gcn_agg(const unsigned* __restrict__ hb,
                                               const float* __restrict__ dinv,
                                               const int* __restrict__ offs,
                                               const int* __restrict__ csr,
                                               const float* __restrict__ bias,
                                               float* __restrict__ out,
                                               int n, int nedges, int do_relu) {
    int wave = threadIdx.x >> 6;
    int lane = threadIdx.x & 63;
    int node = blockIdx.x * 4 + wave;
    if (node >= n) return;
    float di = dinv[node];
    unsigned hv = hb[(long long)node * 64 + lane];
    float ax = di * bf_lo(hv), ay = di * bf_hi(hv);
    int e0 = offs[node];
    int e1 = (node + 1 < n) ? offs[node + 1] : nedges;
    for (int e = e0; e < e1; e += 8) {
        int idx[8];
        #pragma unroll
        for (int j = 0; j < 8; ++j) {
            int ee = e + j;
            idx[j] = csr[ee < e1 ? ee : e1 - 1];
        }
        float w[8]; unsigned u[8];
        #pragma unroll
        for (int j = 0; j < 8; ++j) {
            w[j] = (e + j < e1) ? dinv[idx[j]] : 0.f;
            u[j] = hb[(long long)idx[j] * 64 + lane];
        }
        #pragma unroll
        for (int j = 0; j < 8; ++j) {
            ax = fmaf(w[j], bf_lo(u[j]), ax);
            ay = fmaf(w[j], bf_hi(u[j]), ay);
        }
    }
    float2 b2 = ((const float2*)bias)[lane];
    float ox = fmaf(di, ax, b2.x);
    float oy = fmaf(di, ay, b2.y);
    if (do_relu) { ox = fmaxf(ox, 0.f); oy = fmaxf(oy, 0.f); }
    ((float2*)out)[(long long)node * 64 + lane] = make_float2(ox, oy);
}

// ---------------- loss partials ----------------
__global__ __launch_bounds__(256) void loss_partial(const float* __restrict__ x,
                                                    const int* __restrict__ users,
                                                    const int* __restrict__ items,
                                                    const int* __restrict__ labels,
                                                    const float* __restrict__ clsW,
                                                    const float* __restrict__ clsb,
                                                    const float* __restrict__ duW,
                                                    const float* __restrict__ dub,
                                                    const float* __restrict__ diW,
                                                    const float* __restrict__ dib,
                                                    const int* __restrict__ numUserP,
                                                    float* __restrict__ accum, int Bn) {
    int tid = threadIdx.x;
    int lane = tid & 63;
    int wave = tid >> 6;
    float2 cA = ((const float2*)clsW)[lane];
    float2 cB = ((const float2*)clsW)[64 + lane];
    float2 wU = ((const float2*)duW)[lane];
    float2 wI = ((const float2*)diW)[lane];
    int nu = numUserP[0];
    const float2* x2 = (const float2*)x;
    float bceA = 0.f, cuA = 0.f, ciA = 0.f;
    int base = blockIdx.x * 128 + wave * 32;
    for (int p = 0; p < 32; ++p) {
        int k = base + p;
        if (k >= Bn) break;
        int u = users[k];
        int it = items[k] + nu;
        float2 uv = x2[(long long)u * 64 + lane];
        float2 iv = x2[(long long)it * 64 + lane];
        float zp = uv.x * cA.x + uv.y * cA.y + iv.x * cB.x + iv.y * cB.y;
        float up = uv.x * wU.x + uv.y * wU.y;
        float ip = iv.x * wI.x + iv.y * wI.y;
        #pragma unroll
        for (int o = 32; o > 0; o >>= 1) {
            zp += __shfl_xor(zp, o);
            up += __shfl_xor(up, o);
            ip += __shfl_xor(ip, o);
        }
        if (lane == 0) {
            float z = zp + clsb[0];
            float y = (float)labels[k];
            float sp = fmaxf(z, 0.f) + log1pf(expf(-fabsf(z)));
            bceA += sp - y * z;
            cuA += 1.f / (1.f + expf(-(up + dub[0])));
            ciA += 1.f / (1.f + expf(-(ip + dib[0])));
        }
    }
    __shared__ float sh[12];
    if (lane == 0) { sh[wave * 3 + 0] = bceA; sh[wave * 3 + 1] = cuA; sh[wave * 3 + 2] = ciA; }
    __syncthreads();
    if (tid < 3) {
        float v = sh[tid] + sh[3 + tid] + sh[6 + tid] + sh[9 + tid];
        atomicAdd(&accum[tid], v);
    }
}

__global__ void finalize_k(const float* __restrict__ accum, float* __restrict__ out, float invB) {
    if (threadIdx.x == 0 && blockIdx.x == 0) {
        float clf = (accum[0] + accum[3]) * invB;
        float dom = fabsf((accum[1] - accum[4]) * invB) + fabsf((accum[2] - accum[5]) * invB);
        out[0] = clf + dom;
    }
}

extern "C" void kernel_launch(void* const* d_in, const int* in_sizes, int n_in,
                              void* d_out, int out_size, void* d_ws, size_t ws_size,
                              hipStream_t stream) {
    const float* feats_s = (const float*)d_in[0];
    const float* feats_t = (const float*)d_in[1];
    const float* W1   = (const float*)d_in[2];
    const float* b1   = (const float*)d_in[3];
    const float* W2   = (const float*)d_in[4];
    const float* b2   = (const float*)d_in[5];
    const float* clsW = (const float*)d_in[6];
    const float* clsb = (const float*)d_in[7];
    const float* duW  = (const float*)d_in[8];
    const float* dub  = (const float*)d_in[9];
    const float* diW  = (const float*)d_in[10];
    const float* dib  = (const float*)d_in[11];

    int N = in_sizes[0] / D;
    int E = in_sizes[12];
    int B = in_sizes[16];
    int nb = (N + 255) >> 8;

    char* ws = (char*)d_ws;
    size_t off = 0;
    auto alloc = [&](size_t bytes) -> void* {
        void* p = ws + off;
        off += (bytes + 255) & ~(size_t)255;
        return p;
    };
    float*    dinv   = (float*)alloc((size_t)N * 4);
    int*      offs   = (int*)  alloc((size_t)(N + 1) * 4);
    int*      bcnt   = (int*)  alloc(512 * 4);
    int*      bbase  = (int*)  alloc(513 * 4);
    int*      cursor = (int*)  alloc(512 * 4);
    unsigned* pairs  = (unsigned*)alloc((size_t)E * 4);
    int*      csr    = (int*)  alloc((size_t)E * 4);
    unsigned* hbuf   = (unsigned*)alloc((size_t)N * (D / 2) * 4);
    float*    bufB   = (float*)alloc((size_t)N * D * 4);
    unsigned short* wp1 = (unsigned short*)alloc(16384 * 2);
    unsigned short* wp2 = (unsigned short*)alloc(16384 * 2);
    float*    accum  = (float*)alloc(128);

    hipMemsetAsync(accum, 0, 6 * sizeof(float), stream);
    packW_k<<<2, 256, 0, stream>>>(W1, W2, wp1, wp2);

    int ngb = (N + 63) / 64;

    for (int dm = 0; dm < 2; ++dm) {
        const float* feats = dm ? feats_t : feats_s;
        const int* esrc = (const int*)d_in[dm ? 14 : 12];
        const int* edst = (const int*)d_in[dm ? 15 : 13];
        const int* user = (const int*)d_in[dm ? 19 : 16];
        const int* item = (const int*)d_in[dm ? 20 : 17];
        const int* lab  = (const int*)d_in[dm ? 21 : 18];
        const int* nup  = (const int*)d_in[dm ? 23 : 22];

        hipMemsetAsync(bcnt, 0, 512 * 4, stream);
        bh_k<<<782, 256, 0, stream>>>(edst, bcnt, E);
        scan512_k<<<1, 512, 0, stream>>>(bcnt, bbase, cursor, nb);
        bin_k<<<(E + 2047) / 2048, 256, 0, stream>>>(esrc, edst, cursor, pairs, E);
        csr_build_k<<<nb, 256, 0, stream>>>(pairs, bbase, offs, dinv, csr, N);

        gemm_mfma<<<ngb, 256, 0, stream>>>(feats, wp1, hbuf, N);
        gcn_agg<<<(N + 3) / 4, 256, 0, stream>>>(hbuf, dinv, offs, csr, b1, bufB, N, E, 1);
        gemm_mfma<<<ngb, 256, 0, stream>>>(bufB, wp2, hbuf, N);
        gcn_agg<<<(N + 3) / 4, 256, 0, stream>>>(hbuf, dinv, offs, csr, b2, bufB, N, E, 0);

        loss_partial<<<(B + 127) / 128, 256, 0, stream>>>(bufB, user, item, lab,
                                                          clsW, clsb, duW, dub, diW, dib,
                                                          nup, accum + 3 * dm, B);
    }

    finalize_k<<<1, 64, 0, stream>>>(accum, (float*)d_out, 1.0f / (float)B);
}

// Round 5
// 716.831 us; speedup vs baseline: 2.1465x; 1.0898x over previous
//
#include <hip/hip_runtime.h>

#define D 128

typedef __attribute__((ext_vector_type(8))) short bf16x8;
typedef __attribute__((ext_vector_type(4))) float f32x4;
typedef __attribute__((ext_vector_type(2))) float f32x2;

// ---------- bf16 pack/unpack (RNE) ----------
static __device__ inline unsigned pack_bf16x2(float a, float b) {
    unsigned ua = __float_as_uint(a);
    unsigned ub = __float_as_uint(b);
    ua += 0x7fffu + ((ua >> 16) & 1u);
    ub += 0x7fffu + ((ub >> 16) & 1u);
    return (ua >> 16) | (ub & 0xffff0000u);
}

// ================= CSR build via 2-level bucket sort =================
// bucket b = dst >> 8  (256 nodes per bucket)

__global__ __launch_bounds__(256) void bh_k(const int* __restrict__ dst,
                                            int* __restrict__ bcnt, int E) {
    __shared__ int h[512];
    for (int i = threadIdx.x; i < 512; i += 256) h[i] = 0;
    __syncthreads();
    int stride = gridDim.x * 256;
    for (int e = blockIdx.x * 256 + threadIdx.x; e < E; e += stride)
        atomicAdd(&h[dst[e] >> 8], 1);
    __syncthreads();
    for (int i = threadIdx.x; i < 512; i += 256)
        if (h[i]) atomicAdd(&bcnt[i], h[i]);
}

__global__ __launch_bounds__(512) void scan512_k(const int* __restrict__ bcnt,
                                                 int* __restrict__ bbase,
                                                 int* __restrict__ cursor, int nb) {
    __shared__ int sh[512];
    int t = threadIdx.x;
    int v = (t < nb) ? bcnt[t] : 0;
    sh[t] = v;
    __syncthreads();
    for (int o = 1; o < 512; o <<= 1) {
        int x = (t >= o) ? sh[t - o] : 0;
        __syncthreads();
        sh[t] += x;
        __syncthreads();
    }
    int excl = sh[t] - v;
    if (t < nb) { bbase[t] = excl; cursor[t] = excl; }
    if (t == 0) bbase[nb] = sh[511];
}

__global__ __launch_bounds__(256) void bin_k(const int* __restrict__ src,
                                             const int* __restrict__ dst,
                                             int* __restrict__ cursor,
                                             unsigned* __restrict__ pairs, int E) {
    __shared__ int h[512];
    __shared__ int gb[512];
    int t0 = blockIdx.x * 2048;
    if (t0 >= E) return;
    for (int i = threadIdx.x; i < 512; i += 256) h[i] = 0;
    __syncthreads();
    int rank[8]; unsigned pk[8]; short bk[8];
    #pragma unroll
    for (int j = 0; j < 8; ++j) {
        int e = t0 + j * 256 + threadIdx.x;
        if (e < E) {
            int d = dst[e], s = src[e];
            bk[j] = (short)(d >> 8);
            pk[j] = (unsigned)s | ((unsigned)(d & 255) << 24);
            rank[j] = atomicAdd(&h[d >> 8], 1);
        } else bk[j] = -1;
    }
    __syncthreads();
    for (int i = threadIdx.x; i < 512; i += 256)
        gb[i] = h[i] ? atomicAdd(&cursor[i], h[i]) : 0;
    __syncthreads();
    #pragma unroll
    for (int j = 0; j < 8; ++j)
        if (bk[j] >= 0) pairs[gb[bk[j]] + rank[j]] = pk[j];
}

__global__ __launch_bounds__(256) void csr_build_k(const unsigned* __restrict__ pairs,
                                                   const int* __restrict__ bbase,
                                                   int* __restrict__ offs,
                                                   float* __restrict__ dinv,
                                                   int* __restrict__ csr, int N) {
    __shared__ int lh[256];
    __shared__ int lex[256];
    __shared__ int lc[256];
    int b = blockIdx.x;
    int t = threadIdx.x;
    int e0 = bbase[b], e1 = bbase[b + 1];
    lh[t] = 0; lc[t] = 0;
    __syncthreads();
    for (int e = e0 + t; e < e1; e += 256)
        atomicAdd(&lh[pairs[e] >> 24], 1);
    __syncthreads();
    int v = lh[t];
    lex[t] = v;
    __syncthreads();
    for (int o = 1; o < 256; o <<= 1) {
        int x = (t >= o) ? lex[t - o] : 0;
        __syncthreads();
        lex[t] += x;
        __syncthreads();
    }
    int excl = lex[t] - v;
    int node = (b << 8) + t;
    if (node < N) {
        offs[node] = e0 + excl;
        dinv[node] = rsqrtf((float)(v + 1));
    }
    lex[t] = excl;
    __syncthreads();
    for (int e = e0 + t; e < e1; e += 256) {
        unsigned p = pairs[e];
        int d = p >> 24;
        int pos = lex[d] + atomicAdd(&lc[d], 1);
        csr[e0 + pos] = (int)(p & 0xffffffu);
    }
}

// ================= MFMA GEMM =================
// Pack W (128x128 f32) into B-fragment order for mfma_f32_16x16x32_bf16.
__global__ __launch_bounds__(256) void packW_k(const float* __restrict__ W1,
                                               const float* __restrict__ W2,
                                               unsigned short* __restrict__ wp1,
                                               unsigned short* __restrict__ wp2) {
    const float* W = blockIdx.x ? W2 : W1;
    unsigned short* wp = blockIdx.x ? wp2 : wp1;
    for (int idx = threadIdx.x; idx < 2048; idx += 256) {
        int f = idx >> 6, lane = idx & 63;
        int t = f >> 2, c = f & 3;
        int q = lane >> 4, nn = lane & 15;
        #pragma unroll
        for (int j = 0; j < 8; ++j) {
            unsigned u = __float_as_uint(W[(c * 32 + q * 8 + j) * 128 + t * 16 + nn]);
            u += 0x7fffu + ((u >> 16) & 1u);
            wp[idx * 8 + j] = (unsigned short)(u >> 16);
        }
    }
}

// out (fp8 e4m3, 128B/row) = bf16(x) @ bf16(W); x is f32 (in_bf16=0) or packed bf16 (in_bf16=1)
// block = 4 waves x 16 rows = 64 rows
__global__ __launch_bounds__(256) void gemm_mfma(const void* __restrict__ xin,
                                                 const unsigned short* __restrict__ wp,
                                                 unsigned* __restrict__ outb, int n,
                                                 int in_bf16) {
    __shared__ float cs[64 * 132];   // +4 pad breaks 4-quad bank aliasing
    int tid = threadIdx.x;
    int wave = tid >> 6, lane = tid & 63;
    int quad = lane >> 4, nn = lane & 15;
    long long blockbase = (long long)blockIdx.x * 64;
    long long ar = blockbase + wave * 16 + nn;
    if (ar > n - 1) ar = n - 1;                 // tail clamp (result discarded)

    bf16x8 a[4];
    if (in_bf16) {
        const uint4* xr = (const uint4*)((const unsigned short*)xin + ar * 128);
        #pragma unroll
        for (int c = 0; c < 4; ++c) {
            union { uint4 u; bf16x8 v; } cv;
            cv.u = xr[c * 4 + quad];
            a[c] = cv.v;
        }
    } else {
        const float4* xr = (const float4*)((const float*)xin + ar * 128);
        #pragma unroll
        for (int c = 0; c < 4; ++c) {
            float4 lo = xr[c * 8 + quad * 2];
            float4 hi = xr[c * 8 + quad * 2 + 1];
            union { bf16x8 v; unsigned u[4]; } au;
            au.u[0] = pack_bf16x2(lo.x, lo.y);
            au.u[1] = pack_bf16x2(lo.z, lo.w);
            au.u[2] = pack_bf16x2(hi.x, hi.y);
            au.u[3] = pack_bf16x2(hi.z, hi.w);
            a[c] = au.v;
        }
    }

    f32x4 acc[8];
    #pragma unroll
    for (int t = 0; t < 8; ++t) acc[t] = (f32x4){0.f, 0.f, 0.f, 0.f};

    const bf16x8* wf = (const bf16x8*)wp;
    #pragma unroll
    for (int t = 0; t < 8; ++t) {
        #pragma unroll
        for (int c = 0; c < 4; ++c) {
            bf16x8 b = wf[(t * 4 + c) * 64 + lane];
            acc[t] = __builtin_amdgcn_mfma_f32_16x16x32_bf16(a[c], b, acc[t], 0, 0, 0);
        }
    }

    #pragma unroll
    for (int t = 0; t < 8; ++t) {
        #pragma unroll
        for (int r = 0; r < 4; ++r)
            cs[(wave * 16 + quad * 4 + r) * 132 + t * 16 + nn] = acc[t][r];
    }
    __syncthreads();

    #pragma unroll
    for (int i = 0; i < 8; ++i) {
        int idx = tid + i * 256;
        int r = idx >> 5, c4 = idx & 31;
        const float4 v = *(const float4*)&cs[r * 132 + c4 * 4];
        int pk = __builtin_amdgcn_cvt_pk_fp8_f32(v.x, v.y, 0, false);
        pk = __builtin_amdgcn_cvt_pk_fp8_f32(v.z, v.w, pk, true);
        if (blockbase + r < n)
            outb[(blockbase + r) * 32 + c4] = (unsigned)pk;
    }
}

// ---------------- GCN aggregation (fp8 gather payload) ----------------
// one wave per node; lanes split 32/32 over two edges; lane li owns features 4li..4li+3.
// mode do_relu=1: out = packed bf16 (relu applied); do_relu=0: out = f32.
__global__ __launch_bounds__(256) void gcn_agg8(const unsigned* __restrict__ hb,
                                                const float* __restrict__ dinv,
                                                const int* __restrict__ offs,
                                                const int* __restrict__ csr,
                                                const float* __restrict__ bias,
                                                void* __restrict__ out,
                                                int n, int nedges, int do_relu) {
    int wave = threadIdx.x >> 6;
    int lane = threadIdx.x & 63;
    int node = blockIdx.x * 4 + wave;
    if (node >= n) return;
    int half = lane >> 5, li = lane & 31;
    float di = dinv[node];
    unsigned su = hb[(long long)node * 32 + li];
    f32x2 s01 = __builtin_amdgcn_cvt_pk_f32_fp8((int)su, false);
    f32x2 s23 = __builtin_amdgcn_cvt_pk_f32_fp8((int)su, true);
    float a0 = 0.f, a1 = 0.f, a2 = 0.f, a3 = 0.f;
    int e0 = offs[node];
    int e1 = (node + 1 < n) ? offs[node + 1] : nedges;
    for (int e = e0; e < e1; e += 8) {
        int idx[4];
        #pragma unroll
        for (int j = 0; j < 4; ++j) {
            int ee = e + 2 * j + half;
            idx[j] = csr[ee < e1 ? ee : e1 - 1];
        }
        float w[4]; unsigned u[4];
        #pragma unroll
        for (int j = 0; j < 4; ++j) {
            w[j] = (e + 2 * j + half < e1) ? dinv[idx[j]] : 0.f;
            u[j] = hb[(long long)idx[j] * 32 + li];
        }
        #pragma unroll
        for (int j = 0; j < 4; ++j) {
            f32x2 lo = __builtin_amdgcn_cvt_pk_f32_fp8((int)u[j], false);
            f32x2 hi = __builtin_amdgcn_cvt_pk_f32_fp8((int)u[j], true);
            a0 = fmaf(w[j], lo[0], a0);
            a1 = fmaf(w[j], lo[1], a1);
            a2 = fmaf(w[j], hi[0], a2);
            a3 = fmaf(w[j], hi[1], a3);
        }
    }
    a0 += __shfl_xor(a0, 32);
    a1 += __shfl_xor(a1, 32);
    a2 += __shfl_xor(a2, 32);
    a3 += __shfl_xor(a3, 32);
    // add self term once (after combine)
    a0 = fmaf(di, s01[0], a0);
    a1 = fmaf(di, s01[1], a1);
    a2 = fmaf(di, s23[0], a2);
    a3 = fmaf(di, s23[1], a3);
    float4 b4 = ((const float4*)bias)[li];
    float o0 = fmaf(di, a0, b4.x);
    float o1 = fmaf(di, a1, b4.y);
    float o2 = fmaf(di, a2, b4.z);
    float o3 = fmaf(di, a3, b4.w);
    if (half == 0) {
        if (do_relu) {
            o0 = fmaxf(o0, 0.f); o1 = fmaxf(o1, 0.f);
            o2 = fmaxf(o2, 0.f); o3 = fmaxf(o3, 0.f);
            ((uint2*)out)[(long long)node * 32 + li] =
                make_uint2(pack_bf16x2(o0, o1), pack_bf16x2(o2, o3));
        } else {
            ((float4*)out)[(long long)node * 32 + li] = make_float4(o0, o1, o2, o3);
        }
    }
}

// ---------------- loss partials ----------------
__global__ __launch_bounds__(256) void loss_partial(const float* __restrict__ x,
                                                    const int* __restrict__ users,
                                                    const int* __restrict__ items,
                                                    const int* __restrict__ labels,
                                                    const float* __restrict__ clsW,
                                                    const float* __restrict__ clsb,
                                                    const float* __restrict__ duW,
                                                    const float* __restrict__ dub,
                                                    const float* __restrict__ diW,
                                                    const float* __restrict__ dib,
                                                    const int* __restrict__ numUserP,
                                                    float* __restrict__ accum, int Bn) {
    int tid = threadIdx.x;
    int lane = tid & 63;
    int wave = tid >> 6;
    float2 cA = ((const float2*)clsW)[lane];
    float2 cB = ((const float2*)clsW)[64 + lane];
    float2 wU = ((const float2*)duW)[lane];
    float2 wI = ((const float2*)diW)[lane];
    int nu = numUserP[0];
    const float2* x2 = (const float2*)x;
    float bceA = 0.f, cuA = 0.f, ciA = 0.f;
    int base = blockIdx.x * 128 + wave * 32;
    for (int p = 0; p < 32; ++p) {
        int k = base + p;
        if (k >= Bn) break;
        int u = users[k];
        int it = items[k] + nu;
        float2 uv = x2[(long long)u * 64 + lane];
        float2 iv = x2[(long long)it * 64 + lane];
        float zp = uv.x * cA.x + uv.y * cA.y + iv.x * cB.x + iv.y * cB.y;
        float up = uv.x * wU.x + uv.y * wU.y;
        float ip = iv.x * wI.x + iv.y * wI.y;
        #pragma unroll
        for (int o = 32; o > 0; o >>= 1) {
            zp += __shfl_xor(zp, o);
            up += __shfl_xor(up, o);
            ip += __shfl_xor(ip, o);
        }
        if (lane == 0) {
            float z = zp + clsb[0];
            float y = (float)labels[k];
            float sp = fmaxf(z, 0.f) + log1pf(expf(-fabsf(z)));
            bceA += sp - y * z;
            cuA += 1.f / (1.f + expf(-(up + dub[0])));
            ciA += 1.f / (1.f + expf(-(ip + dib[0])));
        }
    }
    __shared__ float sh[12];
    if (lane == 0) { sh[wave * 3 + 0] = bceA; sh[wave * 3 + 1] = cuA; sh[wave * 3 + 2] = ciA; }
    __syncthreads();
    if (tid < 3) {
        float v = sh[tid] + sh[3 + tid] + sh[6 + tid] + sh[9 + tid];
        atomicAdd(&accum[tid], v);
    }
}

__global__ void finalize_k(const float* __restrict__ accum, float* __restrict__ out, float invB) {
    if (threadIdx.x == 0 && blockIdx.x == 0) {
        float clf = (accum[0] + accum[3]) * invB;
        float dom = fabsf((accum[1] - accum[4]) * invB) + fabsf((accum[2] - accum[5]) * invB);
        out[0] = clf + dom;
    }
}

extern "C" void kernel_launch(void* const* d_in, const int* in_sizes, int n_in,
                              void* d_out, int out_size, void* d_ws, size_t ws_size,
                              hipStream_t stream) {
    const float* feats_s = (const float*)d_in[0];
    const float* feats_t = (const float*)d_in[1];
    const float* W1   = (const float*)d_in[2];
    const float* b1   = (const float*)d_in[3];
    const float* W2   = (const float*)d_in[4];
    const float* b2   = (const float*)d_in[5];
    const float* clsW = (const float*)d_in[6];
    const float* clsb = (const float*)d_in[7];
    const float* duW  = (const float*)d_in[8];
    const float* dub  = (const float*)d_in[9];
    const float* diW  = (const float*)d_in[10];
    const float* dib  = (const float*)d_in[11];

    int N = in_sizes[0] / D;
    int E = in_sizes[12];
    int B = in_sizes[16];
    int nb = (N + 255) >> 8;

    char* ws = (char*)d_ws;
    size_t off = 0;
    auto alloc = [&](size_t bytes) -> void* {
        void* p = ws + off;
        off += (bytes + 255) & ~(size_t)255;
        return p;
    };
    float*    dinv   = (float*)alloc((size_t)N * 4);
    int*      offs   = (int*)  alloc((size_t)(N + 1) * 4);
    int*      bcnt   = (int*)  alloc(512 * 4);
    int*      bbase  = (int*)  alloc(513 * 4);
    int*      cursor = (int*)  alloc(512 * 4);
    unsigned* pairs  = (unsigned*)alloc((size_t)E * 4);
    int*      csr    = (int*)  alloc((size_t)E * 4);
    unsigned* hbuf8  = (unsigned*)alloc((size_t)N * 32 * 4);      // fp8 h, 128B/row
    unsigned* abuf   = (unsigned*)alloc((size_t)N * 64 * 4);      // bf16 agg1 out, 256B/row
    float*    bufB   = (float*)alloc((size_t)N * D * 4);          // f32 agg2 out
    unsigned short* wp1 = (unsigned short*)alloc(16384 * 2);
    unsigned short* wp2 = (unsigned short*)alloc(16384 * 2);
    float*    accum  = (float*)alloc(128);

    hipMemsetAsync(accum, 0, 6 * sizeof(float), stream);
    packW_k<<<2, 256, 0, stream>>>(W1, W2, wp1, wp2);

    int ngb = (N + 63) / 64;

    for (int dm = 0; dm < 2; ++dm) {
        const float* feats = dm ? feats_t : feats_s;
        const int* esrc = (const int*)d_in[dm ? 14 : 12];
        const int* edst = (const int*)d_in[dm ? 15 : 13];
        const int* user = (const int*)d_in[dm ? 19 : 16];
        const int* item = (const int*)d_in[dm ? 20 : 17];
        const int* lab  = (const int*)d_in[dm ? 21 : 18];
        const int* nup  = (const int*)d_in[dm ? 23 : 22];

        hipMemsetAsync(bcnt, 0, 512 * 4, stream);
        bh_k<<<782, 256, 0, stream>>>(edst, bcnt, E);
        scan512_k<<<1, 512, 0, stream>>>(bcnt, bbase, cursor, nb);
        bin_k<<<(E + 2047) / 2048, 256, 0, stream>>>(esrc, edst, cursor, pairs, E);
        csr_build_k<<<nb, 256, 0, stream>>>(pairs, bbase, offs, dinv, csr, N);

        gemm_mfma<<<ngb, 256, 0, stream>>>(feats, wp1, hbuf8, N, 0);
        gcn_agg8<<<(N + 3) / 4, 256, 0, stream>>>(hbuf8, dinv, offs, csr, b1, abuf, N, E, 1);
        gemm_mfma<<<ngb, 256, 0, stream>>>(abuf, wp2, hbuf8, N, 1);
        gcn_agg8<<<(N + 3) / 4, 256, 0, stream>>>(hbuf8, dinv, offs, csr, b2, bufB, N, E, 0);

        loss_partial<<<(B + 127) / 128, 256, 0, stream>>>(bufB, user, item, lab,
                                                          clsW, clsb, duW, dub, diW, dib,
                                                          nup, accum + 3 * dm, B);
    }

    finalize_k<<<1, 64, 0, stream>>>(accum, (float*)d_out, 1.0f / (float)B);
}

// Round 6
// 616.323 us; speedup vs baseline: 2.4965x; 1.1631x over previous
//
#include <hip/hip_runtime.h>

#define D 128

typedef __attribute__((ext_vector_type(8))) short bf16x8;
typedef __attribute__((ext_vector_type(4))) float f32x4;
typedef __attribute__((ext_vector_type(2))) float f32x2;

// ---------- bf16 pack/unpack (RNE) ----------
static __device__ inline unsigned pack_bf16x2(float a, float b) {
    unsigned ua = __float_as_uint(a);
    unsigned ub = __float_as_uint(b);
    ua += 0x7fffu + ((ua >> 16) & 1u);
    ub += 0x7fffu + ((ub >> 16) & 1u);
    return (ua >> 16) | (ub & 0xffff0000u);
}

// ================= CSR build via 2-level bucket sort =================
// bucket b = dst >> 8  (256 nodes per bucket)

__global__ __launch_bounds__(256) void bh_k(const int* __restrict__ dst,
                                            int* __restrict__ bcnt, int E) {
    __shared__ int h[512];
    for (int i = threadIdx.x; i < 512; i += 256) h[i] = 0;
    __syncthreads();
    int stride = gridDim.x * 256;
    for (int e = blockIdx.x * 256 + threadIdx.x; e < E; e += stride)
        atomicAdd(&h[dst[e] >> 8], 1);
    __syncthreads();
    for (int i = threadIdx.x; i < 512; i += 256)
        if (h[i]) atomicAdd(&bcnt[i], h[i]);
}

__global__ __launch_bounds__(512) void scan512_k(const int* __restrict__ bcnt,
                                                 int* __restrict__ bbase,
                                                 int* __restrict__ cursor, int nb) {
    __shared__ int sh[512];
    int t = threadIdx.x;
    int v = (t < nb) ? bcnt[t] : 0;
    sh[t] = v;
    __syncthreads();
    for (int o = 1; o < 512; o <<= 1) {
        int x = (t >= o) ? sh[t - o] : 0;
        __syncthreads();
        sh[t] += x;
        __syncthreads();
    }
    int excl = sh[t] - v;
    if (t < nb) { bbase[t] = excl; cursor[t] = excl; }
    if (t == 0) bbase[nb] = sh[511];
}

__global__ __launch_bounds__(256) void bin_k(const int* __restrict__ src,
                                             const int* __restrict__ dst,
                                             int* __restrict__ cursor,
                                             unsigned* __restrict__ pairs, int E) {
    __shared__ int h[512];
    __shared__ int gb[512];
    int t0 = blockIdx.x * 2048;
    if (t0 >= E) return;
    for (int i = threadIdx.x; i < 512; i += 256) h[i] = 0;
    __syncthreads();
    int rank[8]; unsigned pk[8]; short bk[8];
    #pragma unroll
    for (int j = 0; j < 8; ++j) {
        int e = t0 + j * 256 + threadIdx.x;
        if (e < E) {
            int d = dst[e], s = src[e];
            bk[j] = (short)(d >> 8);
            pk[j] = (unsigned)s | ((unsigned)(d & 255) << 24);
            rank[j] = atomicAdd(&h[d >> 8], 1);
        } else bk[j] = -1;
    }
    __syncthreads();
    for (int i = threadIdx.x; i < 512; i += 256)
        gb[i] = h[i] ? atomicAdd(&cursor[i], h[i]) : 0;
    __syncthreads();
    #pragma unroll
    for (int j = 0; j < 8; ++j)
        if (bk[j] >= 0) pairs[gb[bk[j]] + rank[j]] = pk[j];
}

__global__ __launch_bounds__(256) void csr_build_k(const unsigned* __restrict__ pairs,
                                                   const int* __restrict__ bbase,
                                                   int* __restrict__ offs,
                                                   float* __restrict__ dinv,
                                                   int* __restrict__ csr, int N) {
    __shared__ int lh[256];
    __shared__ int lex[256];
    __shared__ int lc[256];
    int b = blockIdx.x;
    int t = threadIdx.x;
    int e0 = bbase[b], e1 = bbase[b + 1];
    lh[t] = 0; lc[t] = 0;
    __syncthreads();
    for (int e = e0 + t; e < e1; e += 256)
        atomicAdd(&lh[pairs[e] >> 24], 1);
    __syncthreads();
    int v = lh[t];
    lex[t] = v;
    __syncthreads();
    for (int o = 1; o < 256; o <<= 1) {
        int x = (t >= o) ? lex[t - o] : 0;
        __syncthreads();
        lex[t] += x;
        __syncthreads();
    }
    int excl = lex[t] - v;
    int node = (b << 8) + t;
    if (node < N) {
        offs[node] = e0 + excl;
        dinv[node] = rsqrtf((float)(v + 1));
    }
    lex[t] = excl;
    __syncthreads();
    for (int e = e0 + t; e < e1; e += 256) {
        unsigned p = pairs[e];
        int d = p >> 24;
        int pos = lex[d] + atomicAdd(&lc[d], 1);
        csr[e0 + pos] = (int)(p & 0xffffffu);
    }
}

// ================= MFMA GEMM =================
__global__ __launch_bounds__(256) void packW_k(const float* __restrict__ W1,
                                               const float* __restrict__ W2,
                                               unsigned short* __restrict__ wp1,
                                               unsigned short* __restrict__ wp2) {
    const float* W = blockIdx.x ? W2 : W1;
    unsigned short* wp = blockIdx.x ? wp2 : wp1;
    for (int idx = threadIdx.x; idx < 2048; idx += 256) {
        int f = idx >> 6, lane = idx & 63;
        int t = f >> 2, c = f & 3;
        int q = lane >> 4, nn = lane & 15;
        #pragma unroll
        for (int j = 0; j < 8; ++j) {
            unsigned u = __float_as_uint(W[(c * 32 + q * 8 + j) * 128 + t * 16 + nn]);
            u += 0x7fffu + ((u >> 16) & 1u);
            wp[idx * 8 + j] = (unsigned short)(u >> 16);
        }
    }
}

// out (fp8 e4m3, 128B/row) = bf16(x) @ bf16(W); x is f32 (in_bf16=0) or packed bf16 (in_bf16=1)
__global__ __launch_bounds__(256) void gemm_mfma(const void* __restrict__ xin,
                                                 const unsigned short* __restrict__ wp,
                                                 unsigned* __restrict__ outb, int n,
                                                 int in_bf16) {
    __shared__ float cs[64 * 132];
    int tid = threadIdx.x;
    int wave = tid >> 6, lane = tid & 63;
    int quad = lane >> 4, nn = lane & 15;
    long long blockbase = (long long)blockIdx.x * 64;
    long long ar = blockbase + wave * 16 + nn;
    if (ar > n - 1) ar = n - 1;

    bf16x8 a[4];
    if (in_bf16) {
        const uint4* xr = (const uint4*)((const unsigned short*)xin + ar * 128);
        #pragma unroll
        for (int c = 0; c < 4; ++c) {
            union { uint4 u; bf16x8 v; } cv;
            cv.u = xr[c * 4 + quad];
            a[c] = cv.v;
        }
    } else {
        const float4* xr = (const float4*)((const float*)xin + ar * 128);
        #pragma unroll
        for (int c = 0; c < 4; ++c) {
            float4 lo = xr[c * 8 + quad * 2];
            float4 hi = xr[c * 8 + quad * 2 + 1];
            union { bf16x8 v; unsigned u[4]; } au;
            au.u[0] = pack_bf16x2(lo.x, lo.y);
            au.u[1] = pack_bf16x2(lo.z, lo.w);
            au.u[2] = pack_bf16x2(hi.x, hi.y);
            au.u[3] = pack_bf16x2(hi.z, hi.w);
            a[c] = au.v;
        }
    }

    f32x4 acc[8];
    #pragma unroll
    for (int t = 0; t < 8; ++t) acc[t] = (f32x4){0.f, 0.f, 0.f, 0.f};

    const bf16x8* wf = (const bf16x8*)wp;
    #pragma unroll
    for (int t = 0; t < 8; ++t) {
        #pragma unroll
        for (int c = 0; c < 4; ++c) {
            bf16x8 b = wf[(t * 4 + c) * 64 + lane];
            acc[t] = __builtin_amdgcn_mfma_f32_16x16x32_bf16(a[c], b, acc[t], 0, 0, 0);
        }
    }

    #pragma unroll
    for (int t = 0; t < 8; ++t) {
        #pragma unroll
        for (int r = 0; r < 4; ++r)
            cs[(wave * 16 + quad * 4 + r) * 132 + t * 16 + nn] = acc[t][r];
    }
    __syncthreads();

    #pragma unroll
    for (int i = 0; i < 8; ++i) {
        int idx = tid + i * 256;
        int r = idx >> 5, c4 = idx & 31;
        const float4 v = *(const float4*)&cs[r * 132 + c4 * 4];
        int pk = __builtin_amdgcn_cvt_pk_fp8_f32(v.x, v.y, 0, false);
        pk = __builtin_amdgcn_cvt_pk_fp8_f32(v.z, v.w, pk, true);
        if (blockbase + r < n)
            outb[(blockbase + r) * 32 + c4] = (unsigned)pk;
    }
}

// ---------------- GCN aggregation layer 1 (fp8 gather -> bf16 out, relu) ----------------
__global__ __launch_bounds__(256) void gcn_agg8(const unsigned* __restrict__ hb,
                                                const float* __restrict__ dinv,
                                                const int* __restrict__ offs,
                                                const int* __restrict__ csr,
                                                const float* __restrict__ bias,
                                                uint2* __restrict__ out,
                                                int n, int nedges) {
    int wave = threadIdx.x >> 6;
    int lane = threadIdx.x & 63;
    int node = blockIdx.x * 4 + wave;
    if (node >= n) return;
    int half = lane >> 5, li = lane & 31;
    float di = dinv[node];
    unsigned su = hb[(long long)node * 32 + li];
    f32x2 s01 = __builtin_amdgcn_cvt_pk_f32_fp8((int)su, false);
    f32x2 s23 = __builtin_amdgcn_cvt_pk_f32_fp8((int)su, true);
    float a0 = 0.f, a1 = 0.f, a2 = 0.f, a3 = 0.f;
    int e0 = offs[node];
    int e1 = (node + 1 < n) ? offs[node + 1] : nedges;
    for (int e = e0; e < e1; e += 8) {
        int idx[4];
        #pragma unroll
        for (int j = 0; j < 4; ++j) {
            int ee = e + 2 * j + half;
            idx[j] = csr[ee < e1 ? ee : e1 - 1];
        }
        float w[4]; unsigned u[4];
        #pragma unroll
        for (int j = 0; j < 4; ++j) {
            w[j] = (e + 2 * j + half < e1) ? dinv[idx[j]] : 0.f;
            u[j] = hb[(long long)idx[j] * 32 + li];
        }
        #pragma unroll
        for (int j = 0; j < 4; ++j) {
            f32x2 lo = __builtin_amdgcn_cvt_pk_f32_fp8((int)u[j], false);
            f32x2 hi = __builtin_amdgcn_cvt_pk_f32_fp8((int)u[j], true);
            a0 = fmaf(w[j], lo[0], a0);
            a1 = fmaf(w[j], lo[1], a1);
            a2 = fmaf(w[j], hi[0], a2);
            a3 = fmaf(w[j], hi[1], a3);
        }
    }
    a0 += __shfl_xor(a0, 32);
    a1 += __shfl_xor(a1, 32);
    a2 += __shfl_xor(a2, 32);
    a3 += __shfl_xor(a3, 32);
    a0 = fmaf(di, s01[0], a0);
    a1 = fmaf(di, s01[1], a1);
    a2 = fmaf(di, s23[0], a2);
    a3 = fmaf(di, s23[1], a3);
    float4 b4 = ((const float4*)bias)[li];
    if (half == 0) {
        float o0 = fmaxf(fmaf(di, a0, b4.x), 0.f);
        float o1 = fmaxf(fmaf(di, a1, b4.y), 0.f);
        float o2 = fmaxf(fmaf(di, a2, b4.z), 0.f);
        float o3 = fmaxf(fmaf(di, a3, b4.w), 0.f);
        out[(long long)node * 32 + li] =
            make_uint2(pack_bf16x2(o0, o1), pack_bf16x2(o2, o3));
    }
}

// ---------------- GCN aggregation layer 2, fused with per-node loss dots ----------------
// nodeDots[v] = ( dot(row, clsW[sel*128..]), dot(row, sel ? diW : duW) ), sel = v >= numUser
__global__ __launch_bounds__(256) void gcn_agg8_dots(const unsigned* __restrict__ hb,
                                                     const float* __restrict__ dinv,
                                                     const int* __restrict__ offs,
                                                     const int* __restrict__ csr,
                                                     const float* __restrict__ bias,
                                                     const float* __restrict__ clsW,
                                                     const float* __restrict__ duW,
                                                     const float* __restrict__ diW,
                                                     const int* __restrict__ numUserP,
                                                     float2* __restrict__ nodeDots,
                                                     int n, int nedges) {
    int wave = threadIdx.x >> 6;
    int lane = threadIdx.x & 63;
    int node = blockIdx.x * 4 + wave;
    if (node >= n) return;
    int half = lane >> 5, li = lane & 31;
    float di = dinv[node];
    unsigned su = hb[(long long)node * 32 + li];
    f32x2 s01 = __builtin_amdgcn_cvt_pk_f32_fp8((int)su, false);
    f32x2 s23 = __builtin_amdgcn_cvt_pk_f32_fp8((int)su, true);
    float a0 = 0.f, a1 = 0.f, a2 = 0.f, a3 = 0.f;
    int e0 = offs[node];
    int e1 = (node + 1 < n) ? offs[node + 1] : nedges;
    for (int e = e0; e < e1; e += 8) {
        int idx[4];
        #pragma unroll
        for (int j = 0; j < 4; ++j) {
            int ee = e + 2 * j + half;
            idx[j] = csr[ee < e1 ? ee : e1 - 1];
        }
        float w[4]; unsigned u[4];
        #pragma unroll
        for (int j = 0; j < 4; ++j) {
            w[j] = (e + 2 * j + half < e1) ? dinv[idx[j]] : 0.f;
            u[j] = hb[(long long)idx[j] * 32 + li];
        }
        #pragma unroll
        for (int j = 0; j < 4; ++j) {
            f32x2 lo = __builtin_amdgcn_cvt_pk_f32_fp8((int)u[j], false);
            f32x2 hi = __builtin_amdgcn_cvt_pk_f32_fp8((int)u[j], true);
            a0 = fmaf(w[j], lo[0], a0);
            a1 = fmaf(w[j], lo[1], a1);
            a2 = fmaf(w[j], hi[0], a2);
            a3 = fmaf(w[j], hi[1], a3);
        }
    }
    a0 += __shfl_xor(a0, 32);
    a1 += __shfl_xor(a1, 32);
    a2 += __shfl_xor(a2, 32);
    a3 += __shfl_xor(a3, 32);
    a0 = fmaf(di, s01[0], a0);
    a1 = fmaf(di, s01[1], a1);
    a2 = fmaf(di, s23[0], a2);
    a3 = fmaf(di, s23[1], a3);
    float4 b4 = ((const float4*)bias)[li];
    float o0 = fmaf(di, a0, b4.x);
    float o1 = fmaf(di, a1, b4.y);
    float o2 = fmaf(di, a2, b4.z);
    float o3 = fmaf(di, a3, b4.w);
    // per-node dot products with class-selected weights (both halves identical)
    int sel = (node >= numUserP[0]) ? 1 : 0;
    float4 wA = ((const float4*)clsW)[sel * 32 + li];
    float4 wB = ((const float4*)(sel ? diW : duW))[li];
    float p = o0 * wA.x + o1 * wA.y + o2 * wA.z + o3 * wA.w;
    float q = o0 * wB.x + o1 * wB.y + o2 * wB.z + o3 * wB.w;
    #pragma unroll
    for (int o = 16; o > 0; o >>= 1) {
        p += __shfl_xor(p, o);
        q += __shfl_xor(q, o);
    }
    if (lane == 0) nodeDots[node] = make_float2(p, q);
}

// ---------------- pair loss from node dots ----------------
__global__ __launch_bounds__(256) void loss_pairs(const float2* __restrict__ nd,
                                                  const int* __restrict__ users,
                                                  const int* __restrict__ items,
                                                  const int* __restrict__ labels,
                                                  const float* __restrict__ clsb,
                                                  const float* __restrict__ dub,
                                                  const float* __restrict__ dib,
                                                  const int* __restrict__ numUserP,
                                                  float* __restrict__ accum, int Bn) {
    int k = blockIdx.x * 256 + threadIdx.x;
    float bce = 0.f, cu = 0.f, ci = 0.f;
    if (k < Bn) {
        int nu = numUserP[0];
        int u = users[k];
        int t = items[k] + nu;
        float2 ud = nd[u];
        float2 id = nd[t];
        float z = ud.x + id.x + clsb[0];
        float y = (float)labels[k];
        float sp = fmaxf(z, 0.f) + log1pf(expf(-fabsf(z)));
        bce = sp - y * z;
        cu = 1.f / (1.f + expf(-(ud.y + dub[0])));
        ci = 1.f / (1.f + expf(-(id.y + dib[0])));
    }
    #pragma unroll
    for (int o = 32; o > 0; o >>= 1) {
        bce += __shfl_xor(bce, o);
        cu += __shfl_xor(cu, o);
        ci += __shfl_xor(ci, o);
    }
    __shared__ float sh[12];
    int lane = threadIdx.x & 63, wave = threadIdx.x >> 6;
    if (lane == 0) { sh[wave * 3 + 0] = bce; sh[wave * 3 + 1] = cu; sh[wave * 3 + 2] = ci; }
    __syncthreads();
    if (threadIdx.x < 3) {
        float v = sh[threadIdx.x] + sh[3 + threadIdx.x] + sh[6 + threadIdx.x] + sh[9 + threadIdx.x];
        atomicAdd(&accum[threadIdx.x], v);
    }
}

__global__ void finalize_k(const float* __restrict__ accum, float* __restrict__ out, float invB) {
    if (threadIdx.x == 0 && blockIdx.x == 0) {
        float clf = (accum[0] + accum[3]) * invB;
        float dom = fabsf((accum[1] - accum[4]) * invB) + fabsf((accum[2] - accum[5]) * invB);
        out[0] = clf + dom;
    }
}

extern "C" void kernel_launch(void* const* d_in, const int* in_sizes, int n_in,
                              void* d_out, int out_size, void* d_ws, size_t ws_size,
                              hipStream_t stream) {
    const float* feats_s = (const float*)d_in[0];
    const float* feats_t = (const float*)d_in[1];
    const float* W1   = (const float*)d_in[2];
    const float* b1   = (const float*)d_in[3];
    const float* W2   = (const float*)d_in[4];
    const float* b2   = (const float*)d_in[5];
    const float* clsW = (const float*)d_in[6];
    const float* clsb = (const float*)d_in[7];
    const float* duW  = (const float*)d_in[8];
    const float* dub  = (const float*)d_in[9];
    const float* diW  = (const float*)d_in[10];
    const float* dib  = (const float*)d_in[11];

    int N = in_sizes[0] / D;
    int E = in_sizes[12];
    int B = in_sizes[16];
    int nb = (N + 255) >> 8;

    char* ws = (char*)d_ws;
    size_t off = 0;
    auto alloc = [&](size_t bytes) -> void* {
        void* p = ws + off;
        off += (bytes + 255) & ~(size_t)255;
        return p;
    };
    float*    dinv   = (float*)alloc((size_t)N * 4);
    int*      offs   = (int*)  alloc((size_t)(N + 1) * 4);
    int*      bcnt   = (int*)  alloc(512 * 4);
    int*      bbase  = (int*)  alloc(513 * 4);
    int*      cursor = (int*)  alloc(512 * 4);
    unsigned* pairs  = (unsigned*)alloc((size_t)E * 4);
    int*      csr    = (int*)  alloc((size_t)E * 4);
    unsigned* hbuf8  = (unsigned*)alloc((size_t)N * 32 * 4);      // fp8 h, 128B/row
    unsigned* abuf   = (unsigned*)alloc((size_t)N * 64 * 4);      // bf16 agg1 out, 256B/row
    float2*   nodeDots = (float2*)alloc((size_t)N * 8);           // per-node loss dots
    unsigned short* wp1 = (unsigned short*)alloc(16384 * 2);
    unsigned short* wp2 = (unsigned short*)alloc(16384 * 2);
    float*    accum  = (float*)alloc(128);

    hipMemsetAsync(accum, 0, 6 * sizeof(float), stream);
    packW_k<<<2, 256, 0, stream>>>(W1, W2, wp1, wp2);

    int ngb = (N + 63) / 64;

    for (int dm = 0; dm < 2; ++dm) {
        const float* feats = dm ? feats_t : feats_s;
        const int* esrc = (const int*)d_in[dm ? 14 : 12];
        const int* edst = (const int*)d_in[dm ? 15 : 13];
        const int* user = (const int*)d_in[dm ? 19 : 16];
        const int* item = (const int*)d_in[dm ? 20 : 17];
        const int* lab  = (const int*)d_in[dm ? 21 : 18];
        const int* nup  = (const int*)d_in[dm ? 23 : 22];

        hipMemsetAsync(bcnt, 0, 512 * 4, stream);
        bh_k<<<782, 256, 0, stream>>>(edst, bcnt, E);
        scan512_k<<<1, 512, 0, stream>>>(bcnt, bbase, cursor, nb);
        bin_k<<<(E + 2047) / 2048, 256, 0, stream>>>(esrc, edst, cursor, pairs, E);
        csr_build_k<<<nb, 256, 0, stream>>>(pairs, bbase, offs, dinv, csr, N);

        gemm_mfma<<<ngb, 256, 0, stream>>>(feats, wp1, hbuf8, N, 0);
        gcn_agg8<<<(N + 3) / 4, 256, 0, stream>>>(hbuf8, dinv, offs, csr, b1,
                                                  (uint2*)abuf, N, E);
        gemm_mfma<<<ngb, 256, 0, stream>>>(abuf, wp2, hbuf8, N, 1);
        gcn_agg8_dots<<<(N + 3) / 4, 256, 0, stream>>>(hbuf8, dinv, offs, csr, b2,
                                                       clsW, duW, diW, nup, nodeDots, N, E);

        loss_pairs<<<(B + 255) / 256, 256, 0, stream>>>(nodeDots, user, item, lab,
                                                        clsb, dub, dib, nup,
                                                        accum + 3 * dm, B);
    }

    finalize_k<<<1, 64, 0, stream>>>(accum, (float*)d_out, 1.0f / (float)B);
}